// Round 5
// baseline (476.753 us; speedup 1.0000x reference)
//
#include <hip/hip_runtime.h>
#include <cstdint>
#include <cstddef>

typedef unsigned short u16;
typedef unsigned char u8;
typedef unsigned int u32;
typedef __bf16 bf16_t;
typedef bf16_t bf16x8 __attribute__((ext_vector_type(8)));
typedef float f32x4 __attribute__((ext_vector_type(4)));
typedef int i32x8 __attribute__((ext_vector_type(8)));

#define GCH 16          // scan chunks
#define TCH 64          // steps per chunk (1024 / GCH)

static __device__ __forceinline__ float bf2f(u16 v) {
    union { unsigned int u; float f; } cv;
    cv.u = ((unsigned int)v) << 16;
    return cv.f;
}
static __device__ __forceinline__ u16 f2bf(float f) {
    union { float f; unsigned int u; } cv;
    cv.f = f;
    unsigned int r = 0x7fffu + ((cv.u >> 16) & 1u);
    return (u16)((cv.u + r) >> 16);
}

// ---------------------------------------------------------------------------
// weight conversion: mode 0 = fp32->bf16; mode 1 = fp32->fp8 e4m3 of (w*16)
// (x16 prescale keeps N(0,0.02) weights out of e4m3 subnormals; compensated
//  in hardware by MFMA scale_b = 2^-4). grid (blocks, 7).
// ---------------------------------------------------------------------------
struct WSegs { const float* src[7]; void* dst[7]; int n4[7]; int mode[7]; };

__global__ __launch_bounds__(256)
void wconv_all(WSegs s)
{
    const int seg = blockIdx.y;
    const int i = blockIdx.x * 256 + threadIdx.x;
    if (i >= s.n4[seg]) return;
    float4 f = ((const float4*)s.src[seg])[i];
    if (s.mode[seg] == 0) {
        ushort4 o;
        o.x = f2bf(f.x); o.y = f2bf(f.y); o.z = f2bf(f.z); o.w = f2bf(f.w);
        ((ushort4*)s.dst[seg])[i] = o;
    } else {
        const int p0 = __builtin_amdgcn_cvt_pk_fp8_f32(f.x * 16.f, f.y * 16.f, 0, 0);
        const int p1 = __builtin_amdgcn_cvt_pk_fp8_f32(f.z * 16.f, f.w * 16.f, 0, 0);
        ((u32*)s.dst[seg])[i] = (u32)(p0 & 0xFFFF) | ((u32)p1 << 16);
    }
}

// ---------------------------------------------------------------------------
// LayerNorm rows of 1024. IN: 0=fp32, 1=bf16. OUT8: 0=bf16 out, 1=fp8 out.
// ---------------------------------------------------------------------------
template<int BF16IN, int OUT8>
__global__ __launch_bounds__(256)
void ln_kernel(const void* __restrict__ xin, const float* __restrict__ w,
               const float* __restrict__ b, void* __restrict__ out)
{
    const int row = blockIdx.x;
    const int tid = threadIdx.x;
    float vals[4];
    if (BF16IN) {
        const ushort4 uv = ((const ushort4*)((const u16*)xin + (size_t)row * 1024))[tid];
        vals[0] = bf2f(uv.x); vals[1] = bf2f(uv.y);
        vals[2] = bf2f(uv.z); vals[3] = bf2f(uv.w);
    } else {
        const float4 f = ((const float4*)((const float*)xin + (size_t)row * 1024))[tid];
        vals[0] = f.x; vals[1] = f.y; vals[2] = f.z; vals[3] = f.w;
    }
    float s  = vals[0] + vals[1] + vals[2] + vals[3];
    float ss = vals[0]*vals[0] + vals[1]*vals[1] + vals[2]*vals[2] + vals[3]*vals[3];
    for (int off = 32; off; off >>= 1) {
        s  += __shfl_down(s, off, 64);
        ss += __shfl_down(ss, off, 64);
    }
    __shared__ float redS[4], redQ[4];
    if ((tid & 63) == 0) { redS[tid >> 6] = s; redQ[tid >> 6] = ss; }
    __syncthreads();
    s  = redS[0] + redS[1] + redS[2] + redS[3];
    ss = redQ[0] + redQ[1] + redQ[2] + redQ[3];
    const float mu  = s * (1.f / 1024.f);
    const float var = ss * (1.f / 1024.f) - mu * mu;
    const float rs  = rsqrtf(var + 1e-5f);
    const float4 wv = ((const float4*)w)[tid];
    const float4 bv = ((const float4*)b)[tid];
    const float o0 = (vals[0] - mu) * rs * wv.x + bv.x;
    const float o1 = (vals[1] - mu) * rs * wv.y + bv.y;
    const float o2 = (vals[2] - mu) * rs * wv.z + bv.z;
    const float o3 = (vals[3] - mu) * rs * wv.w + bv.w;
    if (OUT8) {
        const int p0 = __builtin_amdgcn_cvt_pk_fp8_f32(o0, o1, 0, 0);
        const int p1 = __builtin_amdgcn_cvt_pk_fp8_f32(o2, o3, 0, 0);
        ((u32*)out)[(size_t)row * 256 + tid] = (u32)(p0 & 0xFFFF) | ((u32)p1 << 16);
    } else {
        ushort4 o;
        o.x = f2bf(o0); o.y = f2bf(o1); o.z = f2bf(o2); o.w = f2bf(o3);
        ((ushort4*)out)[(size_t)row * 1024 / 4 + tid] = o;
    }
}

// ---------------------------------------------------------------------------
// bf16 GEMM: out[M,N] = A[M,K] @ B[N,K]^T, m97 recipe (BK=64) + XOR swizzle +
// transposed grid (x = M-panel for XCD L2 locality).
// DBUF=1: double-buffered LDS, stage(next) issued BEFORE compute(cur), ONE
// __syncthreads per K-step (its full vmcnt/lgkmcnt drain guarantees both
// "next buffer landed" and "cur buffer reads done"). For grid-limited
// dispatches (N=1024 -> 512 blocks = 2/CU = 2 waves/SIMD).
// DBUF=0: verified single-buffer m97 loop for occupancy-rich shapes.
// T14 aux prefetch (EPI 1/4): epilogue residual/gate reads are issued at
// kernel entry into statically-indexed register arrays — at 2 blocks/CU all
// blocks epilogue simultaneously, so late aux reads are fully exposed
// (~10-15 us); early issue hides them under the 60+ us K-loop.
// EPI: 1: bf16(f32(aux1)+acc); 4: f32: bf16(aux1)+bf16(aux2)*acc -> float;
//      5: QKV fused split (N=3072): seg0->outp, seg1->aux1, seg2->aux2
// ---------------------------------------------------------------------------
template<int EPI, int DBUF>
__global__ __launch_bounds__(256)
void gemm_bt(const u16* __restrict__ A, const u16* __restrict__ B,
             int M, int N, int K,
             void* __restrict__ outp,
             const void* __restrict__ aux1, const void* __restrict__ aux2)
{
    __shared__ u16 lA[(1 + DBUF) * 128 * 64];
    __shared__ u16 lB[(1 + DBUF) * 128 * 64];
    const int tid  = threadIdx.x;
    const int wave = tid >> 6;
    const int lane = tid & 63;
    const int q    = lane >> 4;
    const int l16  = lane & 15;
    const long mBase = (long)blockIdx.x * 128;
    const long nBase = (long)blockIdx.y * 128;
    const int wm = (wave >> 1) * 64;
    const int wn = (wave & 1) * 64;

    // T14: issue epilogue aux loads FIRST (statically indexed -> registers)
    float pre1f[4][4][4];
    u16 pre1h[4][4][4], pre2h[4][4][4];
    if (EPI == 1 || EPI == 4) {
        const long colB = nBase + wn + l16;
#pragma unroll
        for (int i = 0; i < 4; ++i)
#pragma unroll
            for (int r = 0; r < 4; ++r) {
                const long rowOff = (mBase + wm + i * 16 + q * 4 + r) * (long)N;
#pragma unroll
                for (int j = 0; j < 4; ++j) {
                    const long idx = rowOff + colB + j * 16;
                    if (EPI == 1) {
                        pre1f[i][r][j] = ((const float*)aux1)[idx];
                    } else {
                        pre1h[i][r][j] = ((const u16*)aux1)[idx];
                        pre2h[i][r][j] = ((const u16*)aux2)[idx];
                    }
                }
            }
    }

    f32x4 acc[4][4];
#pragma unroll
    for (int i = 0; i < 4; ++i)
#pragma unroll
        for (int j = 0; j < 4; ++j)
#pragma unroll
            for (int r = 0; r < 4; ++r) acc[i][j][r] = 0.f;

    const int srow = tid >> 3;
    const int scol = ((tid & 7) ^ (srow & 7)) * 8;
    const int ldsW = wave * 512;
    const int swz = l16 & 7;

    if (DBUF == 0) {
        for (int kb = 0; kb < K; kb += 64) {
            __syncthreads();
#pragma unroll
            for (int c = 0; c < 4; ++c) {
                const int row = c * 32 + srow;
                const u16* ga = A + (mBase + row) * (long)K + kb + scol;
                const u16* gb = B + (nBase + row) * (long)K + kb + scol;
                __builtin_amdgcn_global_load_lds(
                    (const __attribute__((address_space(1))) void*)ga,
                    (__attribute__((address_space(3))) void*)(lA + c * 2048 + ldsW),
                    16, 0, 0);
                __builtin_amdgcn_global_load_lds(
                    (const __attribute__((address_space(1))) void*)gb,
                    (__attribute__((address_space(3))) void*)(lB + c * 2048 + ldsW),
                    16, 0, 0);
            }
            __syncthreads();
#pragma unroll
            for (int ks = 0; ks < 2; ++ks) {
                const int grp = ((ks * 4 + q) ^ swz) * 8;
                bf16x8 af[4], bfm[4];
#pragma unroll
                for (int i = 0; i < 4; ++i) {
                    af[i]  = *(const bf16x8*)(lA + (wm + i * 16 + l16) * 64 + grp);
                    bfm[i] = *(const bf16x8*)(lB + (wn + i * 16 + l16) * 64 + grp);
                }
#pragma unroll
                for (int i = 0; i < 4; ++i)
#pragma unroll
                    for (int j = 0; j < 4; ++j)
                        acc[i][j] = __builtin_amdgcn_mfma_f32_16x16x32_bf16(
                            af[i], bfm[j], acc[i][j], 0, 0, 0);
            }
        }
    } else {
        // ---- double-buffered: stage(next) overlaps compute(cur) ----
        // prologue: stage tile 0 into buf 0
#pragma unroll
        for (int c = 0; c < 4; ++c) {
            const int row = c * 32 + srow;
            const u16* ga = A + (mBase + row) * (long)K + scol;
            const u16* gb = B + (nBase + row) * (long)K + scol;
            __builtin_amdgcn_global_load_lds(
                (const __attribute__((address_space(1))) void*)ga,
                (__attribute__((address_space(3))) void*)(lA + c * 2048 + ldsW),
                16, 0, 0);
            __builtin_amdgcn_global_load_lds(
                (const __attribute__((address_space(1))) void*)gb,
                (__attribute__((address_space(3))) void*)(lB + c * 2048 + ldsW),
                16, 0, 0);
        }
        __syncthreads();            // drains vmcnt -> buf0 (and prefetch) ready
        int cur = 0;
        for (int kb = 0; kb < K; kb += 64) {
            if (kb + 64 < K) {      // issue next tile's loads (async)
                const int nb = (cur ^ 1) * 8192;
#pragma unroll
                for (int c = 0; c < 4; ++c) {
                    const int row = c * 32 + srow;
                    const u16* ga = A + (mBase + row) * (long)K + kb + 64 + scol;
                    const u16* gb = B + (nBase + row) * (long)K + kb + 64 + scol;
                    __builtin_amdgcn_global_load_lds(
                        (const __attribute__((address_space(1))) void*)ga,
                        (__attribute__((address_space(3))) void*)(lA + nb + c * 2048 + ldsW),
                        16, 0, 0);
                    __builtin_amdgcn_global_load_lds(
                        (const __attribute__((address_space(1))) void*)gb,
                        (__attribute__((address_space(3))) void*)(lB + nb + c * 2048 + ldsW),
                        16, 0, 0);
                }
            }
            const u16* bA = lA + cur * 8192;
            const u16* bB = lB + cur * 8192;
#pragma unroll
            for (int ks = 0; ks < 2; ++ks) {
                const int grp = ((ks * 4 + q) ^ swz) * 8;
                bf16x8 af[4], bfm[4];
#pragma unroll
                for (int i = 0; i < 4; ++i) {
                    af[i]  = *(const bf16x8*)(bA + (wm + i * 16 + l16) * 64 + grp);
                    bfm[i] = *(const bf16x8*)(bB + (wn + i * 16 + l16) * 64 + grp);
                }
#pragma unroll
                for (int i = 0; i < 4; ++i)
#pragma unroll
                    for (int j = 0; j < 4; ++j)
                        acc[i][j] = __builtin_amdgcn_mfma_f32_16x16x32_bf16(
                            af[i], bfm[j], acc[i][j], 0, 0, 0);
            }
            // one barrier per step: all waves done reading buf[cur] AND
            // (via full drain) next-tile loads have landed in buf[cur^1]
            __syncthreads();
            cur ^= 1;
        }
    }

    if (EPI == 5) {
        const long seg = nBase >> 10;
        u16* optr = (u16*)(seg == 0 ? outp : seg == 1 ? (void*)aux1 : (void*)aux2);
        const long cb = (nBase & 1023) + wn + l16;
#pragma unroll
        for (int i = 0; i < 4; ++i)
#pragma unroll
            for (int r = 0; r < 4; ++r) {
                const long rowOff = (mBase + wm + i * 16 + q * 4 + r) * 1024 + cb;
#pragma unroll
                for (int j = 0; j < 4; ++j)
                    optr[rowOff + j * 16] = f2bf(acc[i][j][r]);
            }
    } else {
        const long colBase = nBase + wn + l16;
#pragma unroll
        for (int i = 0; i < 4; ++i) {
#pragma unroll
            for (int r = 0; r < 4; ++r) {
                const long row = mBase + wm + i * 16 + q * 4 + r;
                const long rowOff = row * (long)N;
#pragma unroll
                for (int j = 0; j < 4; ++j) {
                    const long idx = rowOff + colBase + j * 16;
                    const float val = acc[i][j][r];
                    if (EPI == 1) {
                        ((u16*)outp)[idx] = f2bf(pre1f[i][r][j] + val);
                    } else {
                        const float t = bf2f(pre1h[i][r][j])
                                      + bf2f(pre2h[i][r][j]) * val;
                        ((float*)outp)[idx] = t;
                    }
                }
            }
        }
    }
}

// ---------------------------------------------------------------------------
// fp8-MX GEMM (FFN-in): out = A[M,K]fp8 @ B[N,K]^T fp8, K=1024, N=5120.
// mfma_scale_f32_16x16x128_f8f6f4, BK=128 bytes, 128-B LDS rows, XOR swizzle
// on 16-B units. scale_a=127 (x1, activations), scale_b=123 (x2^-4,
// compensates weight x16 prescale). Epilogue: n<4096: relu^2 -> kk bf16
// (stride 4096); else sigmoid -> rp bf16 (stride 1024).
// ---------------------------------------------------------------------------
__global__ __launch_bounds__(256)
void gemm_f8(const u8* __restrict__ A, const u8* __restrict__ B,
             int M, int N, int K,
             u16* __restrict__ kk, u16* __restrict__ rp)
{
    __shared__ __align__(16) u8 lA[128 * 128];
    __shared__ __align__(16) u8 lB[128 * 128];
    const int tid  = threadIdx.x;
    const int wave = tid >> 6;
    const int lane = tid & 63;
    const int q    = lane >> 4;
    const int l16  = lane & 15;
    const long mBase = (long)blockIdx.x * 128;
    const long nBase = (long)blockIdx.y * 128;
    const int wm = (wave >> 1) * 64;
    const int wn = (wave & 1) * 64;

    f32x4 acc[4][4];
#pragma unroll
    for (int i = 0; i < 4; ++i)
#pragma unroll
        for (int j = 0; j < 4; ++j)
#pragma unroll
            for (int r = 0; r < 4; ++r) acc[i][j][r] = 0.f;

    const int srow  = tid >> 3;                       // 8 lanes per 128-B row
    const int scolB = ((tid & 7) ^ (srow & 7)) * 16;  // swizzled 16-B unit
    const int ldsW  = wave * 1024;
    const int swz   = l16 & 7;

    for (int kb = 0; kb < K; kb += 128) {
        __syncthreads();
#pragma unroll
        for (int c = 0; c < 4; ++c) {
            const int row = c * 32 + srow;
            const u8* ga = A + (mBase + row) * (long)K + kb + scolB;
            const u8* gb = B + (nBase + row) * (long)K + kb + scolB;
            __builtin_amdgcn_global_load_lds(
                (const __attribute__((address_space(1))) void*)ga,
                (__attribute__((address_space(3))) void*)(lA + c * 4096 + ldsW),
                16, 0, 0);
            __builtin_amdgcn_global_load_lds(
                (const __attribute__((address_space(1))) void*)gb,
                (__attribute__((address_space(3))) void*)(lB + c * 4096 + ldsW),
                16, 0, 0);
        }
        __syncthreads();
        // fragment: lane reads 32 B = 16-B units {2q, 2q+1} XOR swz.
        // XOR flips only unit bit0 within an aligned pair; the resulting
        // k-halves swap identically on A and B (same swz per lane) -> exact.
        const int u0 = ((2 * q) ^ swz) * 16;
        const int u1 = ((2 * q + 1) ^ swz) * 16;
        i32x8 af[4], bfm[4];
#pragma unroll
        for (int i = 0; i < 4; ++i) {
            {
                const u8* base = lA + (wm + i * 16 + l16) * 128;
                const uint4 lo = *(const uint4*)(base + u0);
                const uint4 hi = *(const uint4*)(base + u1);
                af[i][0] = lo.x; af[i][1] = lo.y; af[i][2] = lo.z; af[i][3] = lo.w;
                af[i][4] = hi.x; af[i][5] = hi.y; af[i][6] = hi.z; af[i][7] = hi.w;
            }
            {
                const u8* base = lB + (wn + i * 16 + l16) * 128;
                const uint4 lo = *(const uint4*)(base + u0);
                const uint4 hi = *(const uint4*)(base + u1);
                bfm[i][0] = lo.x; bfm[i][1] = lo.y; bfm[i][2] = lo.z; bfm[i][3] = lo.w;
                bfm[i][4] = hi.x; bfm[i][5] = hi.y; bfm[i][6] = hi.z; bfm[i][7] = hi.w;
            }
        }
#pragma unroll
        for (int i = 0; i < 4; ++i)
#pragma unroll
            for (int j = 0; j < 4; ++j)
                acc[i][j] = __builtin_amdgcn_mfma_scale_f32_16x16x128_f8f6f4(
                    af[i], bfm[j], acc[i][j], 0, 0, 0, 127, 0, 123);
    }

    // epilogue (C/D layout: col=lane&15, row=quad*4+reg — shape-determined)
    u16* optr; long sN, cb;
    if (nBase < 4096) { optr = kk; sN = 4096; cb = nBase + wn + l16; }
    else              { optr = rp; sN = 1024; cb = (nBase - 4096) + wn + l16; }
#pragma unroll
    for (int i = 0; i < 4; ++i)
#pragma unroll
        for (int r = 0; r < 4; ++r) {
            const long rowOff = (mBase + wm + i * 16 + q * 4 + r) * sN + cb;
#pragma unroll
            for (int j = 0; j < 4; ++j) {
                const float val = acc[i][j][r];
                float t;
                if (nBase < 4096) t = val > 0.f ? val * val : 0.f;
                else t = __fdividef(1.f, 1.f + __expf(-val));
                optr[rowOff + j * 16] = f2bf(t);
            }
        }
}

// ---------------------------------------------------------------------------
// Chunked WKV scan, phase 1: per-chunk (a,b,p) summary, both dirs.
// ---------------------------------------------------------------------------
__global__ __launch_bounds__(64)
void wkv_sum(const u16* __restrict__ kbuf, const u16* __restrict__ vbuf,
             const float* __restrict__ decay,
             float* __restrict__ sumA, float* __restrict__ sumB,
             float* __restrict__ sumP)
{
    const int c   = blockIdx.x * 64 + threadIdx.x;
    const int bt  = blockIdx.y;
    const int dir = blockIdx.z & 1;
    const int g   = blockIdx.z >> 1;
    const long base = (long)bt * (1024 * 1024) + c;
    const long stride = dir ? -1024 : 1024;
    long idx = dir ? base + (long)(1023 - g * TCH) * 1024
                   : base + (long)(g * TCH) * 1024;
    const float w = -__expf(decay[c]);
    float a = 0.f, b = 0.f, p = -1e38f;

    float kq[8], vq[8];
#pragma unroll
    for (int j = 0; j < 8; ++j) {
        kq[j] = bf2f(kbuf[idx + j * stride]);
        vq[j] = bf2f(vbuf[idx + j * stride]);
    }
    for (int tb = 0; tb < TCH / 8; ++tb) {
        float kn[8], vn[8];
        if (tb < TCH / 8 - 1) {
#pragma unroll
            for (int j = 0; j < 8; ++j) {
                kn[j] = bf2f(kbuf[idx + (j + 8) * stride]);
                vn[j] = bf2f(vbuf[idx + (j + 8) * stride]);
            }
        }
#pragma unroll
        for (int j = 0; j < 8; ++j) {
            const float kk = kq[j], vv = vq[j];
            const float pw = p + w;
            const float d  = pw - kk;
            const float e  = __expf(-fabsf(d));
            const float f1 = d >= 0.f ? 1.f : e;
            const float f2 = d >= 0.f ? e : 1.f;
            a = f1 * a + f2 * vv;
            b = f1 * b + f2;
            p = fmaxf(pw, kk);
        }
#pragma unroll
        for (int j = 0; j < 8; ++j) { kq[j] = kn[j]; vq[j] = vn[j]; }
        idx += 8 * stride;
    }
    const int sidx = (((dir * GCH + g) * 8 + bt) << 10) + c;
    sumA[sidx] = a; sumB[sidx] = b; sumP[sidx] = p;
}

// ---------------------------------------------------------------------------
// Phase 2 fused: fwd pass -> LDS, bwd pass + sigmoid(r)*0.5*(f+b) -> bf16.
// ---------------------------------------------------------------------------
__global__ __launch_bounds__(64)
void wkv_out2(const u16* __restrict__ kbuf, const u16* __restrict__ vbuf,
              const float* __restrict__ decay, const float* __restrict__ uarr,
              const float* __restrict__ sumA, const float* __restrict__ sumB,
              const float* __restrict__ sumP,
              const u16* __restrict__ rpre, u16* __restrict__ rwkv)
{
    __shared__ float fbuf[TCH * 64];
    const int lane = threadIdx.x;
    const int c   = blockIdx.x * 64 + lane;
    const int bt  = blockIdx.y;
    const int g   = blockIdx.z;
    const long base = (long)bt * (1024 * 1024) + c;
    const long rowBase = base + (long)(g * TCH) * 1024;
    const float w  = -__expf(decay[c]);
    const float uu = uarr[c];

    {
        float a = 0.f, b = 0.f, p = -1e38f;
        for (int gg = 0; gg < g; ++gg) {
            const int sidx = ((gg * 8 + bt) << 10) + c;
            const float a2 = sumA[sidx], b2 = sumB[sidx], p2 = sumP[sidx];
            const float pd = p + w * (float)TCH;
            const float d  = pd - p2;
            const float e  = __expf(-fabsf(d));
            const float x1 = d >= 0.f ? 1.f : e;
            const float x2 = d >= 0.f ? e : 1.f;
            a = x1 * a + x2 * a2;
            b = x1 * b + x2 * b2;
            p = fmaxf(pd, p2);
        }
        long idx = rowBase;
        float kq[8], vq[8];
#pragma unroll
        for (int j = 0; j < 8; ++j) {
            kq[j] = bf2f(kbuf[idx + j * 1024]);
            vq[j] = bf2f(vbuf[idx + j * 1024]);
        }
        for (int tb = 0; tb < TCH / 8; ++tb) {
            float kn[8], vn[8];
            if (tb < TCH / 8 - 1) {
#pragma unroll
                for (int j = 0; j < 8; ++j) {
                    kn[j] = bf2f(kbuf[idx + (j + 8) * 1024]);
                    vn[j] = bf2f(vbuf[idx + (j + 8) * 1024]);
                }
            }
#pragma unroll
            for (int j = 0; j < 8; ++j) {
                const float kk = kq[j], vv = vq[j];
                const float uk = uu + kk;
                const float d1 = p - uk;
                const float e  = __expf(-fabsf(d1));
                const float e1 = d1 >= 0.f ? 1.f : e;
                const float e2 = d1 >= 0.f ? e : 1.f;
                fbuf[(tb * 8 + j) * 64 + lane] =
                    __fdividef(e1 * a + e2 * vv, e1 * b + e2);
                const float pw = p + w;
                const float d2 = pw - kk;
                const float e_ = __expf(-fabsf(d2));
                const float f1 = d2 >= 0.f ? 1.f : e_;
                const float f2 = d2 >= 0.f ? e_ : 1.f;
                a = f1 * a + f2 * vv;
                b = f1 * b + f2;
                p = fmaxf(pw, kk);
            }
#pragma unroll
            for (int j = 0; j < 8; ++j) { kq[j] = kn[j]; vq[j] = vn[j]; }
            idx += 8 * 1024;
        }
    }
    __syncthreads();

    {
        float a = 0.f, b = 0.f, p = -1e38f;
        const int gb = GCH - 1 - g;
        for (int gg = 0; gg < gb; ++gg) {
            const int sidx = (((GCH + gg) * 8 + bt) << 10) + c;
            const float a2 = sumA[sidx], b2 = sumB[sidx], p2 = sumP[sidx];
            const float pd = p + w * (float)TCH;
            const float d  = pd - p2;
            const float e  = __expf(-fabsf(d));
            const float x1 = d >= 0.f ? 1.f : e;
            const float x2 = d >= 0.f ? e : 1.f;
            a = x1 * a + x2 * a2;
            b = x1 * b + x2 * b2;
            p = fmaxf(pd, p2);
        }
        long idx = rowBase + (long)(TCH - 1) * 1024;
        float kq[8], vq[8];
#pragma unroll
        for (int j = 0; j < 8; ++j) {
            kq[j] = bf2f(kbuf[idx - j * 1024]);
            vq[j] = bf2f(vbuf[idx - j * 1024]);
        }
        for (int tb = 0; tb < TCH / 8; ++tb) {
            float kn[8], vn[8];
            if (tb < TCH / 8 - 1) {
#pragma unroll
                for (int j = 0; j < 8; ++j) {
                    kn[j] = bf2f(kbuf[idx - (j + 8) * 1024]);
                    vn[j] = bf2f(vbuf[idx - (j + 8) * 1024]);
                }
            }
#pragma unroll
            for (int j = 0; j < 8; ++j) {
                const long ii = idx - (long)j * 1024;
                const int  tl = TCH - 1 - (tb * 8 + j);
                const float kk = kq[j], vv = vq[j];
                const float uk = uu + kk;
                const float d1 = p - uk;
                const float e  = __expf(-fabsf(d1));
                const float e1 = d1 >= 0.f ? 1.f : e;
                const float e2 = d1 >= 0.f ? e : 1.f;
                const float ob = __fdividef(e1 * a + e2 * vv, e1 * b + e2);
                const float of = fbuf[tl * 64 + lane];
                const float rr = __fdividef(1.f, 1.f + __expf(-bf2f(rpre[ii])));
                rwkv[ii] = f2bf(rr * 0.5f * (of + ob));
                const float pw = p + w;
                const float d2 = pw - kk;
                const float e_ = __expf(-fabsf(d2));
                const float f1 = d2 >= 0.f ? 1.f : e_;
                const float f2 = d2 >= 0.f ? e_ : 1.f;
                a = f1 * a + f2 * vv;
                b = f1 * b + f2;
                p = fmaxf(pw, kk);
            }
#pragma unroll
            for (int j = 0; j < 8; ++j) { kq[j] = kn[j]; vq[j] = vn[j]; }
            idx -= 8 * 1024;
        }
    }
}

// ---------------------------------------------------------------------------
extern "C" void kernel_launch(void* const* d_in, const int* in_sizes, int n_in,
                              void* d_out, int out_size, void* d_ws, size_t ws_size,
                              hipStream_t stream)
{
    (void)in_sizes; (void)n_in; (void)out_size; (void)ws_size;
    const float* x     = (const float*)d_in[0];
    const float* ln1w  = (const float*)d_in[1];
    const float* ln1b  = (const float*)d_in[2];
    const float* ln2w  = (const float*)d_in[3];
    const float* ln2b  = (const float*)d_in[4];
    const float* Wr    = (const float*)d_in[5];
    const float* Wk    = (const float*)d_in[6];
    const float* Wv    = (const float*)d_in[7];
    const float* Wo    = (const float*)d_in[8];
    const float* decay = (const float*)d_in[9];
    const float* uarr  = (const float*)d_in[10];
    const float* Wfk   = (const float*)d_in[11];
    const float* Wfv   = (const float*)d_in[12];
    const float* Wfr   = (const float*)d_in[13];

    const int M = 8192, C = 1024, C4 = 4096;
    const size_t MB = 1024u * 1024u;
    char* ws = (char*)d_ws;
    u16*  X2    = (u16*)(ws);                // [0,16)    x after time-mix (bf16)
    u16*  XN    = (u16*)(ws + 16 * MB);      // [16,32)   xn1 bf16
    u8*   XN8   = (u8*)(ws + 16 * MB);       // [16,24)   xn2 fp8 (reuse, xn1 dead)
    u16*  RP    = (u16*)(ws + 32 * MB);      // [32,48)   r_pre, later ffn sigmoid
    u16*  KB    = (u16*)(ws + 48 * MB);      // [48,64)   k
    u16*  VB    = (u16*)(ws + 64 * MB);      // [64,80)   v
    u16*  RWKV  = (u16*)(ws + 80 * MB);      // [80,96)   combined rwkv
    u16*  KK    = (u16*)(ws + 48 * MB);      // [48,112)  ffn relu^2 key (reuse)
    float* sumA = (float*)(ws + 112 * MB);
    float* sumB = (float*)(ws + 113 * MB);
    float* sumP = (float*)(ws + 114 * MB);
    u16*  WrB   = (u16*)(ws + 116 * MB);     // bf16 [Wr;Wk;Wv] contiguous
    u16*  WkB   = (u16*)(ws + 118 * MB);
    u16*  WvB   = (u16*)(ws + 120 * MB);
    u16*  WoB   = (u16*)(ws + 122 * MB);
    u8*   Wf8   = (u8*)(ws + 124 * MB);      // fp8 [Wfk;Wfr] x16, 5 MB
    u8*   Wfr8  = (u8*)(ws + 128 * MB);
    u16*  WfvB  = (u16*)(ws + 130 * MB);     // bf16 8 MB -> ends 138 MB

    const dim3 blk(256);
    const int n4_1M = C * C / 4, n4_4M = C * C4 / 4;

    WSegs segs;
    segs.src[0] = Wr;  segs.dst[0] = WrB;  segs.n4[0] = n4_1M; segs.mode[0] = 0;
    segs.src[1] = Wk;  segs.dst[1] = WkB;  segs.n4[1] = n4_1M; segs.mode[1] = 0;
    segs.src[2] = Wv;  segs.dst[2] = WvB;  segs.n4[2] = n4_1M; segs.mode[2] = 0;
    segs.src[3] = Wo;  segs.dst[3] = WoB;  segs.n4[3] = n4_1M; segs.mode[3] = 0;
    segs.src[4] = Wfk; segs.dst[4] = Wf8;  segs.n4[4] = n4_4M; segs.mode[4] = 1;
    segs.src[5] = Wfr; segs.dst[5] = Wfr8; segs.n4[5] = n4_1M; segs.mode[5] = 1;
    segs.src[6] = Wfv; segs.dst[6] = WfvB; segs.n4[6] = n4_4M; segs.mode[6] = 0;
    wconv_all<<<dim3(n4_4M / 256, 7), blk, 0, stream>>>(segs);

    ln_kernel<0, 0><<<dim3(M), blk, 0, stream>>>(x, ln1w, ln1b, XN);
    gemm_bt<5, 0><<<dim3(M / 128, 3 * C / 128), blk, 0, stream>>>(
        XN, WrB, M, 3 * C, C, RP, KB, VB);
    wkv_sum<<<dim3(16, 8, 2 * GCH), dim3(64), 0, stream>>>(KB, VB, decay,
                                                           sumA, sumB, sumP);
    wkv_out2<<<dim3(16, 8, GCH), dim3(64), 0, stream>>>(KB, VB, decay, uarr,
                                                        sumA, sumB, sumP,
                                                        RP, RWKV);
    gemm_bt<1, 1><<<dim3(M / 128, C / 128), blk, 0, stream>>>(
        RWKV, WoB, M, C, C, X2, x, nullptr);
    ln_kernel<1, 1><<<dim3(M), blk, 0, stream>>>(X2, ln2w, ln2b, XN8);
    // fp8-MX fused FFN-in: N = 5120, B = [Wfk;Wfr] fp8 (x16 prescale)
    gemm_f8<<<dim3(M / 128, 5 * C / 128), blk, 0, stream>>>(
        XN8, Wf8, M, 5 * C, C, KK, RP);
    gemm_bt<4, 1><<<dim3(M / 128, C / 128), blk, 0, stream>>>(
        KK, WfvB, M, C, C4, d_out, X2, RP);
}

// Round 6
// 416.204 us; speedup vs baseline: 1.1455x; 1.1455x over previous
//
#include <hip/hip_runtime.h>
#include <cstdint>
#include <cstddef>

typedef unsigned short u16;
typedef unsigned char u8;
typedef unsigned int u32;
typedef __bf16 bf16_t;
typedef bf16_t bf16x8 __attribute__((ext_vector_type(8)));
typedef float f32x4 __attribute__((ext_vector_type(4)));
typedef int i32x8 __attribute__((ext_vector_type(8)));

#define GCH 16          // scan chunks
#define TCH 64          // steps per chunk (1024 / GCH)

static __device__ __forceinline__ float bf2f(u16 v) {
    union { unsigned int u; float f; } cv;
    cv.u = ((unsigned int)v) << 16;
    return cv.f;
}
static __device__ __forceinline__ u16 f2bf(float f) {
    union { float f; unsigned int u; } cv;
    cv.f = f;
    unsigned int r = 0x7fffu + ((cv.u >> 16) & 1u);
    return (u16)((cv.u + r) >> 16);
}

// ---------------------------------------------------------------------------
// weight conversion: mode 0 = fp32->bf16; mode 1 = fp32->fp8 e4m3 of (w*16)
// (x16 prescale keeps N(0,0.02) weights out of e4m3 subnormals; compensated
//  in hardware by MFMA scale_b = 2^-4). grid (blocks, 7).
// ---------------------------------------------------------------------------
struct WSegs { const float* src[7]; void* dst[7]; int n4[7]; int mode[7]; };

__global__ __launch_bounds__(256)
void wconv_all(WSegs s)
{
    const int seg = blockIdx.y;
    const int i = blockIdx.x * 256 + threadIdx.x;
    if (i >= s.n4[seg]) return;
    float4 f = ((const float4*)s.src[seg])[i];
    if (s.mode[seg] == 0) {
        ushort4 o;
        o.x = f2bf(f.x); o.y = f2bf(f.y); o.z = f2bf(f.z); o.w = f2bf(f.w);
        ((ushort4*)s.dst[seg])[i] = o;
    } else {
        const int p0 = __builtin_amdgcn_cvt_pk_fp8_f32(f.x * 16.f, f.y * 16.f, 0, 0);
        const int p1 = __builtin_amdgcn_cvt_pk_fp8_f32(f.z * 16.f, f.w * 16.f, 0, 0);
        ((u32*)s.dst[seg])[i] = (u32)(p0 & 0xFFFF) | ((u32)p1 << 16);
    }
}

// ---------------------------------------------------------------------------
// LayerNorm rows of 1024. IN: 0=fp32, 1=bf16. OUT8: 0=bf16 out, 1=fp8 out.
// ---------------------------------------------------------------------------
template<int BF16IN, int OUT8>
__global__ __launch_bounds__(256)
void ln_kernel(const void* __restrict__ xin, const float* __restrict__ w,
               const float* __restrict__ b, void* __restrict__ out)
{
    const int row = blockIdx.x;
    const int tid = threadIdx.x;
    float vals[4];
    if (BF16IN) {
        const ushort4 uv = ((const ushort4*)((const u16*)xin + (size_t)row * 1024))[tid];
        vals[0] = bf2f(uv.x); vals[1] = bf2f(uv.y);
        vals[2] = bf2f(uv.z); vals[3] = bf2f(uv.w);
    } else {
        const float4 f = ((const float4*)((const float*)xin + (size_t)row * 1024))[tid];
        vals[0] = f.x; vals[1] = f.y; vals[2] = f.z; vals[3] = f.w;
    }
    float s  = vals[0] + vals[1] + vals[2] + vals[3];
    float ss = vals[0]*vals[0] + vals[1]*vals[1] + vals[2]*vals[2] + vals[3]*vals[3];
    for (int off = 32; off; off >>= 1) {
        s  += __shfl_down(s, off, 64);
        ss += __shfl_down(ss, off, 64);
    }
    __shared__ float redS[4], redQ[4];
    if ((tid & 63) == 0) { redS[tid >> 6] = s; redQ[tid >> 6] = ss; }
    __syncthreads();
    s  = redS[0] + redS[1] + redS[2] + redS[3];
    ss = redQ[0] + redQ[1] + redQ[2] + redQ[3];
    const float mu  = s * (1.f / 1024.f);
    const float var = ss * (1.f / 1024.f) - mu * mu;
    const float rs  = rsqrtf(var + 1e-5f);
    const float4 wv = ((const float4*)w)[tid];
    const float4 bv = ((const float4*)b)[tid];
    const float o0 = (vals[0] - mu) * rs * wv.x + bv.x;
    const float o1 = (vals[1] - mu) * rs * wv.y + bv.y;
    const float o2 = (vals[2] - mu) * rs * wv.z + bv.z;
    const float o3 = (vals[3] - mu) * rs * wv.w + bv.w;
    if (OUT8) {
        const int p0 = __builtin_amdgcn_cvt_pk_fp8_f32(o0, o1, 0, 0);
        const int p1 = __builtin_amdgcn_cvt_pk_fp8_f32(o2, o3, 0, 0);
        ((u32*)out)[(size_t)row * 256 + tid] = (u32)(p0 & 0xFFFF) | ((u32)p1 << 16);
    } else {
        ushort4 o;
        o.x = f2bf(o0); o.y = f2bf(o1); o.z = f2bf(o2); o.w = f2bf(o3);
        ((ushort4*)out)[(size_t)row * 256 + tid] = o;
    }
}

// ---------------------------------------------------------------------------
// bf16 GEMM: out[M,N] = A[M,K] @ B[N,K]^T, m97 recipe (BK=64) + XOR swizzle +
// transposed grid (x = M-panel for XCD L2 locality).
// DBUF=1: double-buffered LDS, stage(next) issued BEFORE compute(cur), ONE
// __syncthreads per K-step (its full vmcnt/lgkmcnt drain guarantees both
// "next buffer landed" and "cur buffer reads done"). R3-verified: 838 TF at
// 2 blocks/CU on FFN-out, beating single-buffer at 5 blocks/CU (~700 TF) —
// pipeline overlap beats TLP here, so it is used for ALL gemm_bt dispatches.
// DBUF=0: verified single-buffer m97 loop (kept for reference/fallback).
// EPI: 1: bf16(f32(aux1)+acc); 4: f32: bf16(aux1)+bf16(aux2)*acc -> float;
//      5: QKV fused split (N=3072): seg0->outp, seg1->aux1, seg2->aux2
// ---------------------------------------------------------------------------
template<int EPI, int DBUF>
__global__ __launch_bounds__(256)
void gemm_bt(const u16* __restrict__ A, const u16* __restrict__ B,
             int M, int N, int K,
             void* __restrict__ outp,
             const void* __restrict__ aux1, const void* __restrict__ aux2)
{
    __shared__ u16 lA[(1 + DBUF) * 128 * 64];
    __shared__ u16 lB[(1 + DBUF) * 128 * 64];
    const int tid  = threadIdx.x;
    const int wave = tid >> 6;
    const int lane = tid & 63;
    const int q    = lane >> 4;
    const int l16  = lane & 15;
    const long mBase = (long)blockIdx.x * 128;
    const long nBase = (long)blockIdx.y * 128;
    const int wm = (wave >> 1) * 64;
    const int wn = (wave & 1) * 64;

    f32x4 acc[4][4];
#pragma unroll
    for (int i = 0; i < 4; ++i)
#pragma unroll
        for (int j = 0; j < 4; ++j)
#pragma unroll
            for (int r = 0; r < 4; ++r) acc[i][j][r] = 0.f;

    const int srow = tid >> 3;
    const int scol = ((tid & 7) ^ (srow & 7)) * 8;
    const int ldsW = wave * 512;
    const int swz = l16 & 7;

    if (DBUF == 0) {
        for (int kb = 0; kb < K; kb += 64) {
            __syncthreads();
#pragma unroll
            for (int c = 0; c < 4; ++c) {
                const int row = c * 32 + srow;
                const u16* ga = A + (mBase + row) * (long)K + kb + scol;
                const u16* gb = B + (nBase + row) * (long)K + kb + scol;
                __builtin_amdgcn_global_load_lds(
                    (const __attribute__((address_space(1))) void*)ga,
                    (__attribute__((address_space(3))) void*)(lA + c * 2048 + ldsW),
                    16, 0, 0);
                __builtin_amdgcn_global_load_lds(
                    (const __attribute__((address_space(1))) void*)gb,
                    (__attribute__((address_space(3))) void*)(lB + c * 2048 + ldsW),
                    16, 0, 0);
            }
            __syncthreads();
#pragma unroll
            for (int ks = 0; ks < 2; ++ks) {
                const int grp = ((ks * 4 + q) ^ swz) * 8;
                bf16x8 af[4], bfm[4];
#pragma unroll
                for (int i = 0; i < 4; ++i) {
                    af[i]  = *(const bf16x8*)(lA + (wm + i * 16 + l16) * 64 + grp);
                    bfm[i] = *(const bf16x8*)(lB + (wn + i * 16 + l16) * 64 + grp);
                }
#pragma unroll
                for (int i = 0; i < 4; ++i)
#pragma unroll
                    for (int j = 0; j < 4; ++j)
                        acc[i][j] = __builtin_amdgcn_mfma_f32_16x16x32_bf16(
                            af[i], bfm[j], acc[i][j], 0, 0, 0);
            }
        }
    } else {
        // ---- double-buffered: stage(next) overlaps compute(cur) ----
        // prologue: stage tile 0 into buf 0
#pragma unroll
        for (int c = 0; c < 4; ++c) {
            const int row = c * 32 + srow;
            const u16* ga = A + (mBase + row) * (long)K + scol;
            const u16* gb = B + (nBase + row) * (long)K + scol;
            __builtin_amdgcn_global_load_lds(
                (const __attribute__((address_space(1))) void*)ga,
                (__attribute__((address_space(3))) void*)(lA + c * 2048 + ldsW),
                16, 0, 0);
            __builtin_amdgcn_global_load_lds(
                (const __attribute__((address_space(1))) void*)gb,
                (__attribute__((address_space(3))) void*)(lB + c * 2048 + ldsW),
                16, 0, 0);
        }
        __syncthreads();            // drains vmcnt -> buf0 ready
        int cur = 0;
        for (int kb = 0; kb < K; kb += 64) {
            if (kb + 64 < K) {      // issue next tile's loads (async)
                const int nb = (cur ^ 1) * 8192;
#pragma unroll
                for (int c = 0; c < 4; ++c) {
                    const int row = c * 32 + srow;
                    const u16* ga = A + (mBase + row) * (long)K + kb + 64 + scol;
                    const u16* gb = B + (nBase + row) * (long)K + kb + 64 + scol;
                    __builtin_amdgcn_global_load_lds(
                        (const __attribute__((address_space(1))) void*)ga,
                        (__attribute__((address_space(3))) void*)(lA + nb + c * 2048 + ldsW),
                        16, 0, 0);
                    __builtin_amdgcn_global_load_lds(
                        (const __attribute__((address_space(1))) void*)gb,
                        (__attribute__((address_space(3))) void*)(lB + nb + c * 2048 + ldsW),
                        16, 0, 0);
                }
            }
            const u16* bA = lA + cur * 8192;
            const u16* bB = lB + cur * 8192;
#pragma unroll
            for (int ks = 0; ks < 2; ++ks) {
                const int grp = ((ks * 4 + q) ^ swz) * 8;
                bf16x8 af[4], bfm[4];
#pragma unroll
                for (int i = 0; i < 4; ++i) {
                    af[i]  = *(const bf16x8*)(bA + (wm + i * 16 + l16) * 64 + grp);
                    bfm[i] = *(const bf16x8*)(bB + (wn + i * 16 + l16) * 64 + grp);
                }
#pragma unroll
                for (int i = 0; i < 4; ++i)
#pragma unroll
                    for (int j = 0; j < 4; ++j)
                        acc[i][j] = __builtin_amdgcn_mfma_f32_16x16x32_bf16(
                            af[i], bfm[j], acc[i][j], 0, 0, 0);
            }
            // one barrier per step: all waves done reading buf[cur] AND
            // (via full drain) next-tile loads have landed in buf[cur^1]
            __syncthreads();
            cur ^= 1;
        }
    }

    if (EPI == 5) {
        const long seg = nBase >> 10;
        u16* optr = (u16*)(seg == 0 ? outp : seg == 1 ? (void*)aux1 : (void*)aux2);
        const long cb = (nBase & 1023) + wn + l16;
#pragma unroll
        for (int i = 0; i < 4; ++i)
#pragma unroll
            for (int r = 0; r < 4; ++r) {
                const long rowOff = (mBase + wm + i * 16 + q * 4 + r) * 1024 + cb;
#pragma unroll
                for (int j = 0; j < 4; ++j)
                    optr[rowOff + j * 16] = f2bf(acc[i][j][r]);
            }
    } else {
        const long colBase = nBase + wn + l16;
#pragma unroll
        for (int i = 0; i < 4; ++i) {
#pragma unroll
            for (int r = 0; r < 4; ++r) {
                const long row = mBase + wm + i * 16 + q * 4 + r;
                const long rowOff = row * (long)N;
#pragma unroll
                for (int j = 0; j < 4; ++j) {
                    const long idx = rowOff + colBase + j * 16;
                    const float val = acc[i][j][r];
                    if (EPI == 1) {
                        ((u16*)outp)[idx] = f2bf(((const float*)aux1)[idx] + val);
                    } else {
                        const float t = bf2f(((const u16*)aux1)[idx])
                                      + bf2f(((const u16*)aux2)[idx]) * val;
                        ((float*)outp)[idx] = t;
                    }
                }
            }
        }
    }
}

// ---------------------------------------------------------------------------
// fp8-MX GEMM (FFN-in): out = A[M,K]fp8 @ B[N,K]^T fp8, K=1024, N=5120.
// mfma_scale_f32_16x16x128_f8f6f4, BK=128 bytes, 128-B LDS rows, XOR swizzle
// on 16-B units. scale_a=127 (x1, activations), scale_b=123 (x2^-4,
// compensates weight x16 prescale). Epilogue: n<4096: relu^2 -> kk bf16
// (stride 4096); else sigmoid -> rp bf16 (stride 1024).
// ---------------------------------------------------------------------------
__global__ __launch_bounds__(256)
void gemm_f8(const u8* __restrict__ A, const u8* __restrict__ B,
             int M, int N, int K,
             u16* __restrict__ kk, u16* __restrict__ rp)
{
    __shared__ __align__(16) u8 lA[128 * 128];
    __shared__ __align__(16) u8 lB[128 * 128];
    const int tid  = threadIdx.x;
    const int wave = tid >> 6;
    const int lane = tid & 63;
    const int q    = lane >> 4;
    const int l16  = lane & 15;
    const long mBase = (long)blockIdx.x * 128;
    const long nBase = (long)blockIdx.y * 128;
    const int wm = (wave >> 1) * 64;
    const int wn = (wave & 1) * 64;

    f32x4 acc[4][4];
#pragma unroll
    for (int i = 0; i < 4; ++i)
#pragma unroll
        for (int j = 0; j < 4; ++j)
#pragma unroll
            for (int r = 0; r < 4; ++r) acc[i][j][r] = 0.f;

    const int srow  = tid >> 3;                       // 8 lanes per 128-B row
    const int scolB = ((tid & 7) ^ (srow & 7)) * 16;  // swizzled 16-B unit
    const int ldsW  = wave * 1024;
    const int swz   = l16 & 7;

    for (int kb = 0; kb < K; kb += 128) {
        __syncthreads();
#pragma unroll
        for (int c = 0; c < 4; ++c) {
            const int row = c * 32 + srow;
            const u8* ga = A + (mBase + row) * (long)K + kb + scolB;
            const u8* gb = B + (nBase + row) * (long)K + kb + scolB;
            __builtin_amdgcn_global_load_lds(
                (const __attribute__((address_space(1))) void*)ga,
                (__attribute__((address_space(3))) void*)(lA + c * 4096 + ldsW),
                16, 0, 0);
            __builtin_amdgcn_global_load_lds(
                (const __attribute__((address_space(1))) void*)gb,
                (__attribute__((address_space(3))) void*)(lB + c * 4096 + ldsW),
                16, 0, 0);
        }
        __syncthreads();
        // fragment: lane reads 32 B = 16-B units {2q, 2q+1} XOR swz.
        // XOR flips only unit bit0 within an aligned pair; the resulting
        // k-halves swap identically on A and B (same swz per lane) -> exact.
        const int u0 = ((2 * q) ^ swz) * 16;
        const int u1 = ((2 * q + 1) ^ swz) * 16;
        i32x8 af[4], bfm[4];
#pragma unroll
        for (int i = 0; i < 4; ++i) {
            {
                const u8* base = lA + (wm + i * 16 + l16) * 128;
                const uint4 lo = *(const uint4*)(base + u0);
                const uint4 hi = *(const uint4*)(base + u1);
                af[i][0] = lo.x; af[i][1] = lo.y; af[i][2] = lo.z; af[i][3] = lo.w;
                af[i][4] = hi.x; af[i][5] = hi.y; af[i][6] = hi.z; af[i][7] = hi.w;
            }
            {
                const u8* base = lB + (wn + i * 16 + l16) * 128;
                const uint4 lo = *(const uint4*)(base + u0);
                const uint4 hi = *(const uint4*)(base + u1);
                bfm[i][0] = lo.x; bfm[i][1] = lo.y; bfm[i][2] = lo.z; bfm[i][3] = lo.w;
                bfm[i][4] = hi.x; bfm[i][5] = hi.y; bfm[i][6] = hi.z; bfm[i][7] = hi.w;
            }
        }
#pragma unroll
        for (int i = 0; i < 4; ++i)
#pragma unroll
            for (int j = 0; j < 4; ++j)
                acc[i][j] = __builtin_amdgcn_mfma_scale_f32_16x16x128_f8f6f4(
                    af[i], bfm[j], acc[i][j], 0, 0, 0, 127, 0, 123);
    }

    // epilogue (C/D layout: col=lane&15, row=quad*4+reg — shape-determined)
    u16* optr; long sN, cb;
    if (nBase < 4096) { optr = kk; sN = 4096; cb = nBase + wn + l16; }
    else              { optr = rp; sN = 1024; cb = (nBase - 4096) + wn + l16; }
#pragma unroll
    for (int i = 0; i < 4; ++i)
#pragma unroll
        for (int r = 0; r < 4; ++r) {
            const long rowOff = (mBase + wm + i * 16 + q * 4 + r) * sN + cb;
#pragma unroll
            for (int j = 0; j < 4; ++j) {
                const float val = acc[i][j][r];
                float t;
                if (nBase < 4096) t = val > 0.f ? val * val : 0.f;
                else t = __fdividef(1.f, 1.f + __expf(-val));
                optr[rowOff + j * 16] = f2bf(t);
            }
        }
}

// ---------------------------------------------------------------------------
// Chunked WKV scan, phase 1: per-chunk (a,b,p) summary, both dirs.
// ---------------------------------------------------------------------------
__global__ __launch_bounds__(64)
void wkv_sum(const u16* __restrict__ kbuf, const u16* __restrict__ vbuf,
             const float* __restrict__ decay,
             float* __restrict__ sumA, float* __restrict__ sumB,
             float* __restrict__ sumP)
{
    const int c   = blockIdx.x * 64 + threadIdx.x;
    const int bt  = blockIdx.y;
    const int dir = blockIdx.z & 1;
    const int g   = blockIdx.z >> 1;
    const long base = (long)bt * (1024 * 1024) + c;
    const long stride = dir ? -1024 : 1024;
    long idx = dir ? base + (long)(1023 - g * TCH) * 1024
                   : base + (long)(g * TCH) * 1024;
    const float w = -__expf(decay[c]);
    float a = 0.f, b = 0.f, p = -1e38f;

    float kq[8], vq[8];
#pragma unroll
    for (int j = 0; j < 8; ++j) {
        kq[j] = bf2f(kbuf[idx + j * stride]);
        vq[j] = bf2f(vbuf[idx + j * stride]);
    }
    for (int tb = 0; tb < TCH / 8; ++tb) {
        float kn[8], vn[8];
        if (tb < TCH / 8 - 1) {
#pragma unroll
            for (int j = 0; j < 8; ++j) {
                kn[j] = bf2f(kbuf[idx + (j + 8) * stride]);
                vn[j] = bf2f(vbuf[idx + (j + 8) * stride]);
            }
        }
#pragma unroll
        for (int j = 0; j < 8; ++j) {
            const float kk = kq[j], vv = vq[j];
            const float pw = p + w;
            const float d  = pw - kk;
            const float e  = __expf(-fabsf(d));
            const float f1 = d >= 0.f ? 1.f : e;
            const float f2 = d >= 0.f ? e : 1.f;
            a = f1 * a + f2 * vv;
            b = f1 * b + f2;
            p = fmaxf(pw, kk);
        }
#pragma unroll
        for (int j = 0; j < 8; ++j) { kq[j] = kn[j]; vq[j] = vn[j]; }
        idx += 8 * stride;
    }
    const int sidx = (((dir * GCH + g) * 8 + bt) << 10) + c;
    sumA[sidx] = a; sumB[sidx] = b; sumP[sidx] = p;
}

// ---------------------------------------------------------------------------
// Phase 2 fused: fwd pass -> LDS, bwd pass + sigmoid(r)*0.5*(f+b) -> bf16.
// ---------------------------------------------------------------------------
__global__ __launch_bounds__(64)
void wkv_out2(const u16* __restrict__ kbuf, const u16* __restrict__ vbuf,
              const float* __restrict__ decay, const float* __restrict__ uarr,
              const float* __restrict__ sumA, const float* __restrict__ sumB,
              const float* __restrict__ sumP,
              const u16* __restrict__ rpre, u16* __restrict__ rwkv)
{
    __shared__ float fbuf[TCH * 64];
    const int lane = threadIdx.x;
    const int c   = blockIdx.x * 64 + lane;
    const int bt  = blockIdx.y;
    const int g   = blockIdx.z;
    const long base = (long)bt * (1024 * 1024) + c;
    const long rowBase = base + (long)(g * TCH) * 1024;
    const float w  = -__expf(decay[c]);
    const float uu = uarr[c];

    {
        float a = 0.f, b = 0.f, p = -1e38f;
        for (int gg = 0; gg < g; ++gg) {
            const int sidx = ((gg * 8 + bt) << 10) + c;
            const float a2 = sumA[sidx], b2 = sumB[sidx], p2 = sumP[sidx];
            const float pd = p + w * (float)TCH;
            const float d  = pd - p2;
            const float e  = __expf(-fabsf(d));
            const float x1 = d >= 0.f ? 1.f : e;
            const float x2 = d >= 0.f ? e : 1.f;
            a = x1 * a + x2 * a2;
            b = x1 * b + x2 * b2;
            p = fmaxf(pd, p2);
        }
        long idx = rowBase;
        float kq[8], vq[8];
#pragma unroll
        for (int j = 0; j < 8; ++j) {
            kq[j] = bf2f(kbuf[idx + j * 1024]);
            vq[j] = bf2f(vbuf[idx + j * 1024]);
        }
        for (int tb = 0; tb < TCH / 8; ++tb) {
            float kn[8], vn[8];
            if (tb < TCH / 8 - 1) {
#pragma unroll
                for (int j = 0; j < 8; ++j) {
                    kn[j] = bf2f(kbuf[idx + (j + 8) * 1024]);
                    vn[j] = bf2f(vbuf[idx + (j + 8) * 1024]);
                }
            }
#pragma unroll
            for (int j = 0; j < 8; ++j) {
                const float kk = kq[j], vv = vq[j];
                const float uk = uu + kk;
                const float d1 = p - uk;
                const float e  = __expf(-fabsf(d1));
                const float e1 = d1 >= 0.f ? 1.f : e;
                const float e2 = d1 >= 0.f ? e : 1.f;
                fbuf[(tb * 8 + j) * 64 + lane] =
                    __fdividef(e1 * a + e2 * vv, e1 * b + e2);
                const float pw = p + w;
                const float d2 = pw - kk;
                const float e_ = __expf(-fabsf(d2));
                const float f1 = d2 >= 0.f ? 1.f : e_;
                const float f2 = d2 >= 0.f ? e_ : 1.f;
                a = f1 * a + f2 * vv;
                b = f1 * b + f2;
                p = fmaxf(pw, kk);
            }
#pragma unroll
            for (int j = 0; j < 8; ++j) { kq[j] = kn[j]; vq[j] = vn[j]; }
            idx += 8 * 1024;
        }
    }
    __syncthreads();

    {
        float a = 0.f, b = 0.f, p = -1e38f;
        const int gb = GCH - 1 - g;
        for (int gg = 0; gg < gb; ++gg) {
            const int sidx = (((GCH + gg) * 8 + bt) << 10) + c;
            const float a2 = sumA[sidx], b2 = sumB[sidx], p2 = sumP[sidx];
            const float pd = p + w * (float)TCH;
            const float d  = pd - p2;
            const float e  = __expf(-fabsf(d));
            const float x1 = d >= 0.f ? 1.f : e;
            const float x2 = d >= 0.f ? e : 1.f;
            a = x1 * a + x2 * a2;
            b = x1 * b + x2 * b2;
            p = fmaxf(pd, p2);
        }
        long idx = rowBase + (long)(TCH - 1) * 1024;
        float kq[8], vq[8];
#pragma unroll
        for (int j = 0; j < 8; ++j) {
            kq[j] = bf2f(kbuf[idx - j * 1024]);
            vq[j] = bf2f(vbuf[idx - j * 1024]);
        }
        for (int tb = 0; tb < TCH / 8; ++tb) {
            float kn[8], vn[8];
            if (tb < TCH / 8 - 1) {
#pragma unroll
                for (int j = 0; j < 8; ++j) {
                    kn[j] = bf2f(kbuf[idx - (j + 8) * 1024]);
                    vn[j] = bf2f(vbuf[idx - (j + 8) * 1024]);
                }
            }
#pragma unroll
            for (int j = 0; j < 8; ++j) {
                const long ii = idx - (long)j * 1024;
                const int  tl = TCH - 1 - (tb * 8 + j);
                const float kk = kq[j], vv = vq[j];
                const float uk = uu + kk;
                const float d1 = p - uk;
                const float e  = __expf(-fabsf(d1));
                const float e1 = d1 >= 0.f ? 1.f : e;
                const float e2 = d1 >= 0.f ? e : 1.f;
                const float ob = __fdividef(e1 * a + e2 * vv, e1 * b + e2);
                const float of = fbuf[tl * 64 + lane];
                const float rr = __fdividef(1.f, 1.f + __expf(-bf2f(rpre[ii])));
                rwkv[ii] = f2bf(rr * 0.5f * (of + ob));
                const float pw = p + w;
                const float d2 = pw - kk;
                const float e_ = __expf(-fabsf(d2));
                const float f1 = d2 >= 0.f ? 1.f : e_;
                const float f2 = d2 >= 0.f ? e_ : 1.f;
                a = f1 * a + f2 * vv;
                b = f1 * b + f2;
                p = fmaxf(pw, kk);
            }
#pragma unroll
            for (int j = 0; j < 8; ++j) { kq[j] = kn[j]; vq[j] = vn[j]; }
            idx -= 8 * 1024;
        }
    }
}

// ---------------------------------------------------------------------------
extern "C" void kernel_launch(void* const* d_in, const int* in_sizes, int n_in,
                              void* d_out, int out_size, void* d_ws, size_t ws_size,
                              hipStream_t stream)
{
    (void)in_sizes; (void)n_in; (void)out_size; (void)ws_size;
    const float* x     = (const float*)d_in[0];
    const float* ln1w  = (const float*)d_in[1];
    const float* ln1b  = (const float*)d_in[2];
    const float* ln2w  = (const float*)d_in[3];
    const float* ln2b  = (const float*)d_in[4];
    const float* Wr    = (const float*)d_in[5];
    const float* Wk    = (const float*)d_in[6];
    const float* Wv    = (const float*)d_in[7];
    const float* Wo    = (const float*)d_in[8];
    const float* decay = (const float*)d_in[9];
    const float* uarr  = (const float*)d_in[10];
    const float* Wfk   = (const float*)d_in[11];
    const float* Wfv   = (const float*)d_in[12];
    const float* Wfr   = (const float*)d_in[13];

    const int M = 8192, C = 1024, C4 = 4096;
    const size_t MB = 1024u * 1024u;
    char* ws = (char*)d_ws;
    u16*  X2    = (u16*)(ws);                // [0,16)    x after time-mix (bf16)
    u16*  XN    = (u16*)(ws + 16 * MB);      // [16,32)   xn1 bf16
    u8*   XN8   = (u8*)(ws + 16 * MB);       // [16,24)   xn2 fp8 (reuse, xn1 dead)
    u16*  RP    = (u16*)(ws + 32 * MB);      // [32,48)   r_pre, later ffn sigmoid
    u16*  KB    = (u16*)(ws + 48 * MB);      // [48,64)   k
    u16*  VB    = (u16*)(ws + 64 * MB);      // [64,80)   v
    u16*  RWKV  = (u16*)(ws + 80 * MB);      // [80,96)   combined rwkv
    u16*  KK    = (u16*)(ws + 48 * MB);      // [48,112)  ffn relu^2 key (reuse)
    float* sumA = (float*)(ws + 112 * MB);
    float* sumB = (float*)(ws + 113 * MB);
    float* sumP = (float*)(ws + 114 * MB);
    u16*  WrB   = (u16*)(ws + 116 * MB);     // bf16 [Wr;Wk;Wv] contiguous
    u16*  WkB   = (u16*)(ws + 118 * MB);
    u16*  WvB   = (u16*)(ws + 120 * MB);
    u16*  WoB   = (u16*)(ws + 122 * MB);
    u8*   Wf8   = (u8*)(ws + 124 * MB);      // fp8 [Wfk;Wfr] x16, 5 MB
    u8*   Wfr8  = (u8*)(ws + 128 * MB);
    u16*  WfvB  = (u16*)(ws + 130 * MB);     // bf16 8 MB -> ends 138 MB

    const dim3 blk(256);
    const int n4_1M = C * C / 4, n4_4M = C * C4 / 4;

    WSegs segs;
    segs.src[0] = Wr;  segs.dst[0] = WrB;  segs.n4[0] = n4_1M; segs.mode[0] = 0;
    segs.src[1] = Wk;  segs.dst[1] = WkB;  segs.n4[1] = n4_1M; segs.mode[1] = 0;
    segs.src[2] = Wv;  segs.dst[2] = WvB;  segs.n4[2] = n4_1M; segs.mode[2] = 0;
    segs.src[3] = Wo;  segs.dst[3] = WoB;  segs.n4[3] = n4_1M; segs.mode[3] = 0;
    segs.src[4] = Wfk; segs.dst[4] = Wf8;  segs.n4[4] = n4_4M; segs.mode[4] = 1;
    segs.src[5] = Wfr; segs.dst[5] = Wfr8; segs.n4[5] = n4_1M; segs.mode[5] = 1;
    segs.src[6] = Wfv; segs.dst[6] = WfvB; segs.n4[6] = n4_4M; segs.mode[6] = 0;
    wconv_all<<<dim3(n4_4M / 256, 7), blk, 0, stream>>>(segs);

    ln_kernel<0, 0><<<dim3(M), blk, 0, stream>>>(x, ln1w, ln1b, XN);
    gemm_bt<5, 1><<<dim3(M / 128, 3 * C / 128), blk, 0, stream>>>(
        XN, WrB, M, 3 * C, C, RP, KB, VB);
    wkv_sum<<<dim3(16, 8, 2 * GCH), dim3(64), 0, stream>>>(KB, VB, decay,
                                                           sumA, sumB, sumP);
    wkv_out2<<<dim3(16, 8, GCH), dim3(64), 0, stream>>>(KB, VB, decay, uarr,
                                                        sumA, sumB, sumP,
                                                        RP, RWKV);
    gemm_bt<1, 1><<<dim3(M / 128, C / 128), blk, 0, stream>>>(
        RWKV, WoB, M, C, C, X2, x, nullptr);
    ln_kernel<1, 1><<<dim3(M), blk, 0, stream>>>(X2, ln2w, ln2b, XN8);
    // fp8-MX fused FFN-in: N = 5120, B = [Wfk;Wfr] fp8 (x16 prescale)
    gemm_f8<<<dim3(M / 128, 5 * C / 128), blk, 0, stream>>>(
        XN8, Wf8, M, 5 * C, C, KK, RP);
    gemm_bt<4, 1><<<dim3(M / 128, C / 128), blk, 0, stream>>>(
        KK, WfvB, M, C, C4, d_out, X2, RP);
}

// Round 7
// 411.013 us; speedup vs baseline: 1.1599x; 1.0126x over previous
//
#include <hip/hip_runtime.h>
#include <cstdint>
#include <cstddef>

typedef unsigned short u16;
typedef unsigned char u8;
typedef unsigned int u32;
typedef __bf16 bf16_t;
typedef bf16_t bf16x8 __attribute__((ext_vector_type(8)));
typedef float f32x4 __attribute__((ext_vector_type(4)));
typedef int i32x8 __attribute__((ext_vector_type(8)));

#define GCH 16          // scan chunks
#define TCH 64          // steps per chunk (1024 / GCH)

static __device__ __forceinline__ float bf2f(u16 v) {
    union { unsigned int u; float f; } cv;
    cv.u = ((unsigned int)v) << 16;
    return cv.f;
}
static __device__ __forceinline__ u16 f2bf(float f) {
    union { float f; unsigned int u; } cv;
    cv.f = f;
    unsigned int r = 0x7fffu + ((cv.u >> 16) & 1u);
    return (u16)((cv.u + r) >> 16);
}

// ---------------------------------------------------------------------------
// weight conversion: mode 0 = fp32->bf16; mode 1 = fp32->fp8 e4m3 of (w*16)
// (x16 prescale keeps N(0,0.02) weights out of e4m3 subnormals; compensated
//  in hardware by MFMA scale_b = 2^-4). grid (blocks, 7).
// ---------------------------------------------------------------------------
struct WSegs { const float* src[7]; void* dst[7]; int n4[7]; int mode[7]; };

__global__ __launch_bounds__(256)
void wconv_all(WSegs s)
{
    const int seg = blockIdx.y;
    const int i = blockIdx.x * 256 + threadIdx.x;
    if (i >= s.n4[seg]) return;
    float4 f = ((const float4*)s.src[seg])[i];
    if (s.mode[seg] == 0) {
        ushort4 o;
        o.x = f2bf(f.x); o.y = f2bf(f.y); o.z = f2bf(f.z); o.w = f2bf(f.w);
        ((ushort4*)s.dst[seg])[i] = o;
    } else {
        const int p0 = __builtin_amdgcn_cvt_pk_fp8_f32(f.x * 16.f, f.y * 16.f, 0, 0);
        const int p1 = __builtin_amdgcn_cvt_pk_fp8_f32(f.z * 16.f, f.w * 16.f, 0, 0);
        ((u32*)s.dst[seg])[i] = (u32)(p0 & 0xFFFF) | ((u32)p1 << 16);
    }
}

// ---------------------------------------------------------------------------
// LayerNorm rows of 1024. IN: 0=fp32, 1=bf16. OUT8: 0=bf16 out, 1=fp8 out.
// ---------------------------------------------------------------------------
template<int BF16IN, int OUT8>
__global__ __launch_bounds__(256)
void ln_kernel(const void* __restrict__ xin, const float* __restrict__ w,
               const float* __restrict__ b, void* __restrict__ out)
{
    const int row = blockIdx.x;
    const int tid = threadIdx.x;
    float vals[4];
    if (BF16IN) {
        const ushort4 uv = ((const ushort4*)((const u16*)xin + (size_t)row * 1024))[tid];
        vals[0] = bf2f(uv.x); vals[1] = bf2f(uv.y);
        vals[2] = bf2f(uv.z); vals[3] = bf2f(uv.w);
    } else {
        const float4 f = ((const float4*)((const float*)xin + (size_t)row * 1024))[tid];
        vals[0] = f.x; vals[1] = f.y; vals[2] = f.z; vals[3] = f.w;
    }
    float s  = vals[0] + vals[1] + vals[2] + vals[3];
    float ss = vals[0]*vals[0] + vals[1]*vals[1] + vals[2]*vals[2] + vals[3]*vals[3];
    for (int off = 32; off; off >>= 1) {
        s  += __shfl_down(s, off, 64);
        ss += __shfl_down(ss, off, 64);
    }
    __shared__ float redS[4], redQ[4];
    if ((tid & 63) == 0) { redS[tid >> 6] = s; redQ[tid >> 6] = ss; }
    __syncthreads();
    s  = redS[0] + redS[1] + redS[2] + redS[3];
    ss = redQ[0] + redQ[1] + redQ[2] + redQ[3];
    const float mu  = s * (1.f / 1024.f);
    const float var = ss * (1.f / 1024.f) - mu * mu;
    const float rs  = rsqrtf(var + 1e-5f);
    const float4 wv = ((const float4*)w)[tid];
    const float4 bv = ((const float4*)b)[tid];
    const float o0 = (vals[0] - mu) * rs * wv.x + bv.x;
    const float o1 = (vals[1] - mu) * rs * wv.y + bv.y;
    const float o2 = (vals[2] - mu) * rs * wv.z + bv.z;
    const float o3 = (vals[3] - mu) * rs * wv.w + bv.w;
    if (OUT8) {
        const int p0 = __builtin_amdgcn_cvt_pk_fp8_f32(o0, o1, 0, 0);
        const int p1 = __builtin_amdgcn_cvt_pk_fp8_f32(o2, o3, 0, 0);
        ((u32*)out)[(size_t)row * 256 + tid] = (u32)(p0 & 0xFFFF) | ((u32)p1 << 16);
    } else {
        ushort4 o;
        o.x = f2bf(o0); o.y = f2bf(o1); o.z = f2bf(o2); o.w = f2bf(o3);
        ((ushort4*)out)[(size_t)row * 256 + tid] = o;
    }
}

// ---------------------------------------------------------------------------
// bf16 GEMM: out[M,N] = A[M,K] @ B[N,K]^T, m97 recipe (BK=64) + XOR swizzle +
// transposed grid (x = M-panel for XCD L2 locality).
// DBUF=0: verified single-buffer m97 loop (occupancy-rich shapes, K=1024).
// DBUF=1: R3-verified 1-deep dbuf: stage(next) before compute(cur), one
//   __syncthreads per K-step. 838 TF on grid-limited N=1024 shapes.
// DBUF=2: lean 2-deep pipeline for the long-K grid-limited dispatch
//   (FFN-out, K=4096, 2 blocks/CU). TWO tiles in flight (16 outstanding
//   global_load_lds/wave); counted s_waitcnt vmcnt(8) waits only tile t+1,
//   giving its loads a FULL extra compute phase of cover (~1500+ cy vs the
//   ~500 cy a 1-deep dbuf provides against ~900 cy HBM latency).
//   Raw s_barrier for cross-wave publish/free; compiler-only memory fences
//   (asm ""::: "memory", zero instructions) pin memory-op order WITHOUT
//   sched_barrier(0)'s full order-pinning (R4's regression: VALU 20->41%).
//   Pre-barrier lgkmcnt waits on MFMA operands already drain ds_reads, so
//   raw s_barrier (no explicit lgkmcnt) is safe.
// EPI: 1: bf16(f32(aux1)+acc); 4: f32: bf16(aux1)+bf16(aux2)*acc -> float;
//      5: QKV fused split (N=3072): seg0->outp, seg1->aux1, seg2->aux2
// ---------------------------------------------------------------------------
template<int EPI, int DBUF>
__global__ __launch_bounds__(256)
void gemm_bt(const u16* __restrict__ A, const u16* __restrict__ B,
             int M, int N, int K,
             void* __restrict__ outp,
             const void* __restrict__ aux1, const void* __restrict__ aux2)
{
    __shared__ u16 lA[(DBUF ? 2 : 1) * 128 * 64];
    __shared__ u16 lB[(DBUF ? 2 : 1) * 128 * 64];
    const int tid  = threadIdx.x;
    const int wave = tid >> 6;
    const int lane = tid & 63;
    const int q    = lane >> 4;
    const int l16  = lane & 15;
    const long mBase = (long)blockIdx.x * 128;
    const long nBase = (long)blockIdx.y * 128;
    const int wm = (wave >> 1) * 64;
    const int wn = (wave & 1) * 64;

    f32x4 acc[4][4];
#pragma unroll
    for (int i = 0; i < 4; ++i)
#pragma unroll
        for (int j = 0; j < 4; ++j)
#pragma unroll
            for (int r = 0; r < 4; ++r) acc[i][j][r] = 0.f;

    const int srow = tid >> 3;
    const int scol = ((tid & 7) ^ (srow & 7)) * 8;
    const int ldsW = wave * 512;
    const int swz = l16 & 7;

    if (DBUF == 0) {
        for (int kb = 0; kb < K; kb += 64) {
            __syncthreads();
#pragma unroll
            for (int c = 0; c < 4; ++c) {
                const int row = c * 32 + srow;
                const u16* ga = A + (mBase + row) * (long)K + kb + scol;
                const u16* gb = B + (nBase + row) * (long)K + kb + scol;
                __builtin_amdgcn_global_load_lds(
                    (const __attribute__((address_space(1))) void*)ga,
                    (__attribute__((address_space(3))) void*)(lA + c * 2048 + ldsW),
                    16, 0, 0);
                __builtin_amdgcn_global_load_lds(
                    (const __attribute__((address_space(1))) void*)gb,
                    (__attribute__((address_space(3))) void*)(lB + c * 2048 + ldsW),
                    16, 0, 0);
            }
            __syncthreads();
#pragma unroll
            for (int ks = 0; ks < 2; ++ks) {
                const int grp = ((ks * 4 + q) ^ swz) * 8;
                bf16x8 af[4], bfm[4];
#pragma unroll
                for (int i = 0; i < 4; ++i) {
                    af[i]  = *(const bf16x8*)(lA + (wm + i * 16 + l16) * 64 + grp);
                    bfm[i] = *(const bf16x8*)(lB + (wn + i * 16 + l16) * 64 + grp);
                }
#pragma unroll
                for (int i = 0; i < 4; ++i)
#pragma unroll
                    for (int j = 0; j < 4; ++j)
                        acc[i][j] = __builtin_amdgcn_mfma_f32_16x16x32_bf16(
                            af[i], bfm[j], acc[i][j], 0, 0, 0);
            }
        }
    } else {
        auto stage = [&](int kb, int bufsel) {
#pragma unroll
            for (int c = 0; c < 4; ++c) {
                const int row = c * 32 + srow;
                const u16* ga = A + (mBase + row) * (long)K + kb + scol;
                const u16* gb = B + (nBase + row) * (long)K + kb + scol;
                __builtin_amdgcn_global_load_lds(
                    (const __attribute__((address_space(1))) void*)ga,
                    (__attribute__((address_space(3))) void*)(lA + bufsel * 8192 + c * 2048 + ldsW),
                    16, 0, 0);
                __builtin_amdgcn_global_load_lds(
                    (const __attribute__((address_space(1))) void*)gb,
                    (__attribute__((address_space(3))) void*)(lB + bufsel * 8192 + c * 2048 + ldsW),
                    16, 0, 0);
            }
        };
        auto compute = [&](int bufsel) {
            const u16* bA = lA + bufsel * 8192;
            const u16* bB = lB + bufsel * 8192;
#pragma unroll
            for (int ks = 0; ks < 2; ++ks) {
                const int grp = ((ks * 4 + q) ^ swz) * 8;
                bf16x8 af[4], bfm[4];
#pragma unroll
                for (int i = 0; i < 4; ++i) {
                    af[i]  = *(const bf16x8*)(bA + (wm + i * 16 + l16) * 64 + grp);
                    bfm[i] = *(const bf16x8*)(bB + (wn + i * 16 + l16) * 64 + grp);
                }
#pragma unroll
                for (int i = 0; i < 4; ++i)
#pragma unroll
                    for (int j = 0; j < 4; ++j)
                        acc[i][j] = __builtin_amdgcn_mfma_f32_16x16x32_bf16(
                            af[i], bfm[j], acc[i][j], 0, 0, 0);
            }
        };

        if (DBUF == 1) {
            // ---- R3-verified 1-deep dbuf ----
            stage(0, 0);
            __syncthreads();            // drains vmcnt -> buf0 ready
            int cur = 0;
            for (int kb = 0; kb < K; kb += 64) {
                if (kb + 64 < K) stage(kb + 64, cur ^ 1);
                compute(cur);
                // one barrier per step: all waves done reading buf[cur] AND
                // (full drain) next-tile loads landed in buf[cur^1]
                __syncthreads();
                cur ^= 1;
            }
        } else {
            // ---- lean 2-deep pipeline (counted vmcnt, raw barriers) ----
            const int nt = K >> 6;       // #K-tiles (>= 2)
            stage(0, 0);
            stage(64, 1);                // 16 loads in flight
            asm volatile("s_waitcnt vmcnt(8)" ::: "memory");  // tile0 landed
            __builtin_amdgcn_s_barrier();
            asm volatile("" ::: "memory");
            int cur = 0;
            for (int t = 0; t < nt - 2; ++t) {
                compute(cur);            // tile t from buf[cur]
                __builtin_amdgcn_s_barrier();   // all waves done with buf[cur]
                asm volatile("" ::: "memory");
                stage((t + 2) << 6, cur);       // tile t+2 -> freed buffer
                asm volatile("s_waitcnt vmcnt(8)" ::: "memory"); // tile t+1 landed
                __builtin_amdgcn_s_barrier();   // tile t+1 published
                asm volatile("" ::: "memory");
                cur ^= 1;
            }
            compute(cur);                // tile nt-2
            asm volatile("s_waitcnt vmcnt(0)" ::: "memory");
            __builtin_amdgcn_s_barrier();       // tile nt-1 published
            asm volatile("" ::: "memory");
            compute(cur ^ 1);            // tile nt-1
        }
    }

    if (EPI == 5) {
        const long seg = nBase >> 10;
        u16* optr = (u16*)(seg == 0 ? outp : seg == 1 ? (void*)aux1 : (void*)aux2);
        const long cb = (nBase & 1023) + wn + l16;
#pragma unroll
        for (int i = 0; i < 4; ++i)
#pragma unroll
            for (int r = 0; r < 4; ++r) {
                const long rowOff = (mBase + wm + i * 16 + q * 4 + r) * 1024 + cb;
#pragma unroll
                for (int j = 0; j < 4; ++j)
                    optr[rowOff + j * 16] = f2bf(acc[i][j][r]);
            }
    } else {
        const long colBase = nBase + wn + l16;
#pragma unroll
        for (int i = 0; i < 4; ++i) {
#pragma unroll
            for (int r = 0; r < 4; ++r) {
                const long row = mBase + wm + i * 16 + q * 4 + r;
                const long rowOff = row * (long)N;
#pragma unroll
                for (int j = 0; j < 4; ++j) {
                    const long idx = rowOff + colBase + j * 16;
                    const float val = acc[i][j][r];
                    if (EPI == 1) {
                        ((u16*)outp)[idx] = f2bf(((const float*)aux1)[idx] + val);
                    } else {
                        const float t = bf2f(((const u16*)aux1)[idx])
                                      + bf2f(((const u16*)aux2)[idx]) * val;
                        ((float*)outp)[idx] = t;
                    }
                }
            }
        }
    }
}

// ---------------------------------------------------------------------------
// fp8-MX GEMM (FFN-in): out = A[M,K]fp8 @ B[N,K]^T fp8, K=1024, N=5120.
// mfma_scale_f32_16x16x128_f8f6f4, BK=128 bytes, 128-B LDS rows, XOR swizzle
// on 16-B units. scale_a=127 (x1, activations), scale_b=123 (x2^-4,
// compensates weight x16 prescale). Epilogue: n<4096: relu^2 -> kk bf16
// (stride 4096); else sigmoid -> rp bf16 (stride 1024).
// ---------------------------------------------------------------------------
__global__ __launch_bounds__(256)
void gemm_f8(const u8* __restrict__ A, const u8* __restrict__ B,
             int M, int N, int K,
             u16* __restrict__ kk, u16* __restrict__ rp)
{
    __shared__ __align__(16) u8 lA[128 * 128];
    __shared__ __align__(16) u8 lB[128 * 128];
    const int tid  = threadIdx.x;
    const int wave = tid >> 6;
    const int lane = tid & 63;
    const int q    = lane >> 4;
    const int l16  = lane & 15;
    const long mBase = (long)blockIdx.x * 128;
    const long nBase = (long)blockIdx.y * 128;
    const int wm = (wave >> 1) * 64;
    const int wn = (wave & 1) * 64;

    f32x4 acc[4][4];
#pragma unroll
    for (int i = 0; i < 4; ++i)
#pragma unroll
        for (int j = 0; j < 4; ++j)
#pragma unroll
            for (int r = 0; r < 4; ++r) acc[i][j][r] = 0.f;

    const int srow  = tid >> 3;                       // 8 lanes per 128-B row
    const int scolB = ((tid & 7) ^ (srow & 7)) * 16;  // swizzled 16-B unit
    const int ldsW  = wave * 1024;
    const int swz   = l16 & 7;

    for (int kb = 0; kb < K; kb += 128) {
        __syncthreads();
#pragma unroll
        for (int c = 0; c < 4; ++c) {
            const int row = c * 32 + srow;
            const u8* ga = A + (mBase + row) * (long)K + kb + scolB;
            const u8* gb = B + (nBase + row) * (long)K + kb + scolB;
            __builtin_amdgcn_global_load_lds(
                (const __attribute__((address_space(1))) void*)ga,
                (__attribute__((address_space(3))) void*)(lA + c * 4096 + ldsW),
                16, 0, 0);
            __builtin_amdgcn_global_load_lds(
                (const __attribute__((address_space(1))) void*)gb,
                (__attribute__((address_space(3))) void*)(lB + c * 4096 + ldsW),
                16, 0, 0);
        }
        __syncthreads();
        // fragment: lane reads 32 B = 16-B units {2q, 2q+1} XOR swz.
        // XOR flips only unit bit0 within an aligned pair; the resulting
        // k-halves swap identically on A and B (same swz per lane) -> exact.
        const int u0 = ((2 * q) ^ swz) * 16;
        const int u1 = ((2 * q + 1) ^ swz) * 16;
        i32x8 af[4], bfm[4];
#pragma unroll
        for (int i = 0; i < 4; ++i) {
            {
                const u8* base = lA + (wm + i * 16 + l16) * 128;
                const uint4 lo = *(const uint4*)(base + u0);
                const uint4 hi = *(const uint4*)(base + u1);
                af[i][0] = lo.x; af[i][1] = lo.y; af[i][2] = lo.z; af[i][3] = lo.w;
                af[i][4] = hi.x; af[i][5] = hi.y; af[i][6] = hi.z; af[i][7] = hi.w;
            }
            {
                const u8* base = lB + (wn + i * 16 + l16) * 128;
                const uint4 lo = *(const uint4*)(base + u0);
                const uint4 hi = *(const uint4*)(base + u1);
                bfm[i][0] = lo.x; bfm[i][1] = lo.y; bfm[i][2] = lo.z; bfm[i][3] = lo.w;
                bfm[i][4] = hi.x; bfm[i][5] = hi.y; bfm[i][6] = hi.z; bfm[i][7] = hi.w;
            }
        }
#pragma unroll
        for (int i = 0; i < 4; ++i)
#pragma unroll
            for (int j = 0; j < 4; ++j)
                acc[i][j] = __builtin_amdgcn_mfma_scale_f32_16x16x128_f8f6f4(
                    af[i], bfm[j], acc[i][j], 0, 0, 0, 127, 0, 123);
    }

    // epilogue (C/D layout: col=lane&15, row=quad*4+reg — shape-determined)
    u16* optr; long sN, cb;
    if (nBase < 4096) { optr = kk; sN = 4096; cb = nBase + wn + l16; }
    else              { optr = rp; sN = 1024; cb = (nBase - 4096) + wn + l16; }
#pragma unroll
    for (int i = 0; i < 4; ++i)
#pragma unroll
        for (int r = 0; r < 4; ++r) {
            const long rowOff = (mBase + wm + i * 16 + q * 4 + r) * sN + cb;
#pragma unroll
            for (int j = 0; j < 4; ++j) {
                const float val = acc[i][j][r];
                float t;
                if (nBase < 4096) t = val > 0.f ? val * val : 0.f;
                else t = __fdividef(1.f, 1.f + __expf(-val));
                optr[rowOff + j * 16] = f2bf(t);
            }
        }
}

// ---------------------------------------------------------------------------
// Chunked WKV scan, phase 1: per-chunk (a,b,p) summary, both dirs.
// ---------------------------------------------------------------------------
__global__ __launch_bounds__(64)
void wkv_sum(const u16* __restrict__ kbuf, const u16* __restrict__ vbuf,
             const float* __restrict__ decay,
             float* __restrict__ sumA, float* __restrict__ sumB,
             float* __restrict__ sumP)
{
    const int c   = blockIdx.x * 64 + threadIdx.x;
    const int bt  = blockIdx.y;
    const int dir = blockIdx.z & 1;
    const int g   = blockIdx.z >> 1;
    const long base = (long)bt * (1024 * 1024) + c;
    const long stride = dir ? -1024 : 1024;
    long idx = dir ? base + (long)(1023 - g * TCH) * 1024
                   : base + (long)(g * TCH) * 1024;
    const float w = -__expf(decay[c]);
    float a = 0.f, b = 0.f, p = -1e38f;

    float kq[8], vq[8];
#pragma unroll
    for (int j = 0; j < 8; ++j) {
        kq[j] = bf2f(kbuf[idx + j * stride]);
        vq[j] = bf2f(vbuf[idx + j * stride]);
    }
    for (int tb = 0; tb < TCH / 8; ++tb) {
        float kn[8], vn[8];
        if (tb < TCH / 8 - 1) {
#pragma unroll
            for (int j = 0; j < 8; ++j) {
                kn[j] = bf2f(kbuf[idx + (j + 8) * stride]);
                vn[j] = bf2f(vbuf[idx + (j + 8) * stride]);
            }
        }
#pragma unroll
        for (int j = 0; j < 8; ++j) {
            const float kk = kq[j], vv = vq[j];
            const float pw = p + w;
            const float d  = pw - kk;
            const float e  = __expf(-fabsf(d));
            const float f1 = d >= 0.f ? 1.f : e;
            const float f2 = d >= 0.f ? e : 1.f;
            a = f1 * a + f2 * vv;
            b = f1 * b + f2;
            p = fmaxf(pw, kk);
        }
#pragma unroll
        for (int j = 0; j < 8; ++j) { kq[j] = kn[j]; vq[j] = vn[j]; }
        idx += 8 * stride;
    }
    const int sidx = (((dir * GCH + g) * 8 + bt) << 10) + c;
    sumA[sidx] = a; sumB[sidx] = b; sumP[sidx] = p;
}

// ---------------------------------------------------------------------------
// Phase 2 fused: fwd pass -> LDS, bwd pass + sigmoid(r)*0.5*(f+b) -> bf16.
// ---------------------------------------------------------------------------
__global__ __launch_bounds__(64)
void wkv_out2(const u16* __restrict__ kbuf, const u16* __restrict__ vbuf,
              const float* __restrict__ decay, const float* __restrict__ uarr,
              const float* __restrict__ sumA, const float* __restrict__ sumB,
              const float* __restrict__ sumP,
              const u16* __restrict__ rpre, u16* __restrict__ rwkv)
{
    __shared__ float fbuf[TCH * 64];
    const int lane = threadIdx.x;
    const int c   = blockIdx.x * 64 + lane;
    const int bt  = blockIdx.y;
    const int g   = blockIdx.z;
    const long base = (long)bt * (1024 * 1024) + c;
    const long rowBase = base + (long)(g * TCH) * 1024;
    const float w  = -__expf(decay[c]);
    const float uu = uarr[c];

    {
        float a = 0.f, b = 0.f, p = -1e38f;
        for (int gg = 0; gg < g; ++gg) {
            const int sidx = ((gg * 8 + bt) << 10) + c;
            const float a2 = sumA[sidx], b2 = sumB[sidx], p2 = sumP[sidx];
            const float pd = p + w * (float)TCH;
            const float d  = pd - p2;
            const float e  = __expf(-fabsf(d));
            const float x1 = d >= 0.f ? 1.f : e;
            const float x2 = d >= 0.f ? e : 1.f;
            a = x1 * a + x2 * a2;
            b = x1 * b + x2 * b2;
            p = fmaxf(pd, p2);
        }
        long idx = rowBase;
        float kq[8], vq[8];
#pragma unroll
        for (int j = 0; j < 8; ++j) {
            kq[j] = bf2f(kbuf[idx + j * 1024]);
            vq[j] = bf2f(vbuf[idx + j * 1024]);
        }
        for (int tb = 0; tb < TCH / 8; ++tb) {
            float kn[8], vn[8];
            if (tb < TCH / 8 - 1) {
#pragma unroll
                for (int j = 0; j < 8; ++j) {
                    kn[j] = bf2f(kbuf[idx + (j + 8) * 1024]);
                    vn[j] = bf2f(vbuf[idx + (j + 8) * 1024]);
                }
            }
#pragma unroll
            for (int j = 0; j < 8; ++j) {
                const float kk = kq[j], vv = vq[j];
                const float uk = uu + kk;
                const float d1 = p - uk;
                const float e  = __expf(-fabsf(d1));
                const float e1 = d1 >= 0.f ? 1.f : e;
                const float e2 = d1 >= 0.f ? e : 1.f;
                fbuf[(tb * 8 + j) * 64 + lane] =
                    __fdividef(e1 * a + e2 * vv, e1 * b + e2);
                const float pw = p + w;
                const float d2 = pw - kk;
                const float e_ = __expf(-fabsf(d2));
                const float f1 = d2 >= 0.f ? 1.f : e_;
                const float f2 = d2 >= 0.f ? e_ : 1.f;
                a = f1 * a + f2 * vv;
                b = f1 * b + f2;
                p = fmaxf(pw, kk);
            }
#pragma unroll
            for (int j = 0; j < 8; ++j) { kq[j] = kn[j]; vq[j] = vn[j]; }
            idx += 8 * 1024;
        }
    }
    __syncthreads();

    {
        float a = 0.f, b = 0.f, p = -1e38f;
        const int gb = GCH - 1 - g;
        for (int gg = 0; gg < gb; ++gg) {
            const int sidx = (((GCH + gg) * 8 + bt) << 10) + c;
            const float a2 = sumA[sidx], b2 = sumB[sidx], p2 = sumP[sidx];
            const float pd = p + w * (float)TCH;
            const float d  = pd - p2;
            const float e  = __expf(-fabsf(d));
            const float x1 = d >= 0.f ? 1.f : e;
            const float x2 = d >= 0.f ? e : 1.f;
            a = x1 * a + x2 * a2;
            b = x1 * b + x2 * b2;
            p = fmaxf(pd, p2);
        }
        long idx = rowBase + (long)(TCH - 1) * 1024;
        float kq[8], vq[8];
#pragma unroll
        for (int j = 0; j < 8; ++j) {
            kq[j] = bf2f(kbuf[idx - j * 1024]);
            vq[j] = bf2f(vbuf[idx - j * 1024]);
        }
        for (int tb = 0; tb < TCH / 8; ++tb) {
            float kn[8], vn[8];
            if (tb < TCH / 8 - 1) {
#pragma unroll
                for (int j = 0; j < 8; ++j) {
                    kn[j] = bf2f(kbuf[idx - (j + 8) * 1024]);
                    vn[j] = bf2f(vbuf[idx - (j + 8) * 1024]);
                }
            }
#pragma unroll
            for (int j = 0; j < 8; ++j) {
                const long ii = idx - (long)j * 1024;
                const int  tl = TCH - 1 - (tb * 8 + j);
                const float kk = kq[j], vv = vq[j];
                const float uk = uu + kk;
                const float d1 = p - uk;
                const float e  = __expf(-fabsf(d1));
                const float e1 = d1 >= 0.f ? 1.f : e;
                const float e2 = d1 >= 0.f ? e : 1.f;
                const float ob = __fdividef(e1 * a + e2 * vv, e1 * b + e2);
                const float of = fbuf[tl * 64 + lane];
                const float rr = __fdividef(1.f, 1.f + __expf(-bf2f(rpre[ii])));
                rwkv[ii] = f2bf(rr * 0.5f * (of + ob));
                const float pw = p + w;
                const float d2 = pw - kk;
                const float e_ = __expf(-fabsf(d2));
                const float f1 = d2 >= 0.f ? 1.f : e_;
                const float f2 = d2 >= 0.f ? e_ : 1.f;
                a = f1 * a + f2 * vv;
                b = f1 * b + f2;
                p = fmaxf(pw, kk);
            }
#pragma unroll
            for (int j = 0; j < 8; ++j) { kq[j] = kn[j]; vq[j] = vn[j]; }
            idx -= 8 * 1024;
        }
    }
}

// ---------------------------------------------------------------------------
extern "C" void kernel_launch(void* const* d_in, const int* in_sizes, int n_in,
                              void* d_out, int out_size, void* d_ws, size_t ws_size,
                              hipStream_t stream)
{
    (void)in_sizes; (void)n_in; (void)out_size; (void)ws_size;
    const float* x     = (const float*)d_in[0];
    const float* ln1w  = (const float*)d_in[1];
    const float* ln1b  = (const float*)d_in[2];
    const float* ln2w  = (const float*)d_in[3];
    const float* ln2b  = (const float*)d_in[4];
    const float* Wr    = (const float*)d_in[5];
    const float* Wk    = (const float*)d_in[6];
    const float* Wv    = (const float*)d_in[7];
    const float* Wo    = (const float*)d_in[8];
    const float* decay = (const float*)d_in[9];
    const float* uarr  = (const float*)d_in[10];
    const float* Wfk   = (const float*)d_in[11];
    const float* Wfv   = (const float*)d_in[12];
    const float* Wfr   = (const float*)d_in[13];

    const int M = 8192, C = 1024, C4 = 4096;
    const size_t MB = 1024u * 1024u;
    char* ws = (char*)d_ws;
    u16*  X2    = (u16*)(ws);                // [0,16)    x after time-mix (bf16)
    u16*  XN    = (u16*)(ws + 16 * MB);      // [16,32)   xn1 bf16
    u8*   XN8   = (u8*)(ws + 16 * MB);       // [16,24)   xn2 fp8 (reuse, xn1 dead)
    u16*  RP    = (u16*)(ws + 32 * MB);      // [32,48)   r_pre, later ffn sigmoid
    u16*  KB    = (u16*)(ws + 48 * MB);      // [48,64)   k
    u16*  VB    = (u16*)(ws + 64 * MB);      // [64,80)   v
    u16*  RWKV  = (u16*)(ws + 80 * MB);      // [80,96)   combined rwkv
    u16*  KK    = (u16*)(ws + 48 * MB);      // [48,112)  ffn relu^2 key (reuse)
    float* sumA = (float*)(ws + 112 * MB);
    float* sumB = (float*)(ws + 113 * MB);
    float* sumP = (float*)(ws + 114 * MB);
    u16*  WrB   = (u16*)(ws + 116 * MB);     // bf16 [Wr;Wk;Wv] contiguous
    u16*  WkB   = (u16*)(ws + 118 * MB);
    u16*  WvB   = (u16*)(ws + 120 * MB);
    u16*  WoB   = (u16*)(ws + 122 * MB);
    u8*   Wf8   = (u8*)(ws + 124 * MB);      // fp8 [Wfk;Wfr] x16, 5 MB
    u8*   Wfr8  = (u8*)(ws + 128 * MB);
    u16*  WfvB  = (u16*)(ws + 130 * MB);     // bf16 8 MB -> ends 138 MB

    const dim3 blk(256);
    const int n4_1M = C * C / 4, n4_4M = C * C4 / 4;

    WSegs segs;
    segs.src[0] = Wr;  segs.dst[0] = WrB;  segs.n4[0] = n4_1M; segs.mode[0] = 0;
    segs.src[1] = Wk;  segs.dst[1] = WkB;  segs.n4[1] = n4_1M; segs.mode[1] = 0;
    segs.src[2] = Wv;  segs.dst[2] = WvB;  segs.n4[2] = n4_1M; segs.mode[2] = 0;
    segs.src[3] = Wo;  segs.dst[3] = WoB;  segs.n4[3] = n4_1M; segs.mode[3] = 0;
    segs.src[4] = Wfk; segs.dst[4] = Wf8;  segs.n4[4] = n4_4M; segs.mode[4] = 1;
    segs.src[5] = Wfr; segs.dst[5] = Wfr8; segs.n4[5] = n4_1M; segs.mode[5] = 1;
    segs.src[6] = Wfv; segs.dst[6] = WfvB; segs.n4[6] = n4_4M; segs.mode[6] = 0;
    wconv_all<<<dim3(n4_4M / 256, 7), blk, 0, stream>>>(segs);

    ln_kernel<0, 0><<<dim3(M), blk, 0, stream>>>(x, ln1w, ln1b, XN);
    gemm_bt<5, 0><<<dim3(M / 128, 3 * C / 128), blk, 0, stream>>>(
        XN, WrB, M, 3 * C, C, RP, KB, VB);
    wkv_sum<<<dim3(16, 8, 2 * GCH), dim3(64), 0, stream>>>(KB, VB, decay,
                                                           sumA, sumB, sumP);
    wkv_out2<<<dim3(16, 8, GCH), dim3(64), 0, stream>>>(KB, VB, decay, uarr,
                                                        sumA, sumB, sumP,
                                                        RP, RWKV);
    gemm_bt<1, 1><<<dim3(M / 128, C / 128), blk, 0, stream>>>(
        RWKV, WoB, M, C, C, X2, x, nullptr);
    ln_kernel<1, 1><<<dim3(M), blk, 0, stream>>>(X2, ln2w, ln2b, XN8);
    // fp8-MX fused FFN-in: N = 5120, B = [Wfk;Wfr] fp8 (x16 prescale)
    gemm_f8<<<dim3(M / 128, 5 * C / 128), blk, 0, stream>>>(
        XN8, Wf8, M, 5 * C, C, KK, RP);
    gemm_bt<4, 2><<<dim3(M / 128, C / 128), blk, 0, stream>>>(
        KK, WfvB, M, C, C4, d_out, X2, RP);
}

// Round 8
// 400.221 us; speedup vs baseline: 1.1912x; 1.0270x over previous
//
#include <hip/hip_runtime.h>
#include <cstdint>
#include <cstddef>

typedef unsigned short u16;
typedef unsigned char u8;
typedef unsigned int u32;
typedef __bf16 bf16_t;
typedef bf16_t bf16x8 __attribute__((ext_vector_type(8)));
typedef float f32x4 __attribute__((ext_vector_type(4)));
typedef int i32x8 __attribute__((ext_vector_type(8)));

#define GCH 16          // scan chunks
#define TCH 64          // steps per chunk (1024 / GCH)

static __device__ __forceinline__ float bf2f(u16 v) {
    union { unsigned int u; float f; } cv;
    cv.u = ((unsigned int)v) << 16;
    return cv.f;
}
static __device__ __forceinline__ u16 f2bf(float f) {
    union { float f; unsigned int u; } cv;
    cv.f = f;
    unsigned int r = 0x7fffu + ((cv.u >> 16) & 1u);
    return (u16)((cv.u + r) >> 16);
}

// ---------------------------------------------------------------------------
// weight conversion: mode 0 = fp32->bf16; mode 1 = fp32->fp8 e4m3 of (w*16)
// (x16 prescale keeps N(0,0.02) weights out of e4m3 subnormals; compensated
//  in hardware by MFMA scale_b = 2^-4). grid (blocks, 7).
// ---------------------------------------------------------------------------
struct WSegs { const float* src[7]; void* dst[7]; int n4[7]; int mode[7]; };

__global__ __launch_bounds__(256)
void wconv_all(WSegs s)
{
    const int seg = blockIdx.y;
    const int i = blockIdx.x * 256 + threadIdx.x;
    if (i >= s.n4[seg]) return;
    float4 f = ((const float4*)s.src[seg])[i];
    if (s.mode[seg] == 0) {
        ushort4 o;
        o.x = f2bf(f.x); o.y = f2bf(f.y); o.z = f2bf(f.z); o.w = f2bf(f.w);
        ((ushort4*)s.dst[seg])[i] = o;
    } else {
        const int p0 = __builtin_amdgcn_cvt_pk_fp8_f32(f.x * 16.f, f.y * 16.f, 0, 0);
        const int p1 = __builtin_amdgcn_cvt_pk_fp8_f32(f.z * 16.f, f.w * 16.f, 0, 0);
        ((u32*)s.dst[seg])[i] = (u32)(p0 & 0xFFFF) | ((u32)p1 << 16);
    }
}

// ---------------------------------------------------------------------------
// LayerNorm rows of 1024. IN: 0=fp32, 1=bf16. OUT8: 0=bf16 out, 1=fp8 out.
// ---------------------------------------------------------------------------
template<int BF16IN, int OUT8>
__global__ __launch_bounds__(256)
void ln_kernel(const void* __restrict__ xin, const float* __restrict__ w,
               const float* __restrict__ b, void* __restrict__ out)
{
    const int row = blockIdx.x;
    const int tid = threadIdx.x;
    float vals[4];
    if (BF16IN) {
        const ushort4 uv = ((const ushort4*)((const u16*)xin + (size_t)row * 1024))[tid];
        vals[0] = bf2f(uv.x); vals[1] = bf2f(uv.y);
        vals[2] = bf2f(uv.z); vals[3] = bf2f(uv.w);
    } else {
        const float4 f = ((const float4*)((const float*)xin + (size_t)row * 1024))[tid];
        vals[0] = f.x; vals[1] = f.y; vals[2] = f.z; vals[3] = f.w;
    }
    float s  = vals[0] + vals[1] + vals[2] + vals[3];
    float ss = vals[0]*vals[0] + vals[1]*vals[1] + vals[2]*vals[2] + vals[3]*vals[3];
    for (int off = 32; off; off >>= 1) {
        s  += __shfl_down(s, off, 64);
        ss += __shfl_down(ss, off, 64);
    }
    __shared__ float redS[4], redQ[4];
    if ((tid & 63) == 0) { redS[tid >> 6] = s; redQ[tid >> 6] = ss; }
    __syncthreads();
    s  = redS[0] + redS[1] + redS[2] + redS[3];
    ss = redQ[0] + redQ[1] + redQ[2] + redQ[3];
    const float mu  = s * (1.f / 1024.f);
    const float var = ss * (1.f / 1024.f) - mu * mu;
    const float rs  = rsqrtf(var + 1e-5f);
    const float4 wv = ((const float4*)w)[tid];
    const float4 bv = ((const float4*)b)[tid];
    const float o0 = (vals[0] - mu) * rs * wv.x + bv.x;
    const float o1 = (vals[1] - mu) * rs * wv.y + bv.y;
    const float o2 = (vals[2] - mu) * rs * wv.z + bv.z;
    const float o3 = (vals[3] - mu) * rs * wv.w + bv.w;
    if (OUT8) {
        const int p0 = __builtin_amdgcn_cvt_pk_fp8_f32(o0, o1, 0, 0);
        const int p1 = __builtin_amdgcn_cvt_pk_fp8_f32(o2, o3, 0, 0);
        ((u32*)out)[(size_t)row * 256 + tid] = (u32)(p0 & 0xFFFF) | ((u32)p1 << 16);
    } else {
        ushort4 o;
        o.x = f2bf(o0); o.y = f2bf(o1); o.z = f2bf(o2); o.w = f2bf(o3);
        ((ushort4*)out)[(size_t)row * 256 + tid] = o;
    }
}

// ---------------------------------------------------------------------------
// bf16 GEMM: out[M,N] = A[M,K] @ B[N,K]^T, m97 recipe (BK=64) + XOR swizzle +
// transposed grid (x = M-panel for XCD L2 locality).
// Per-dispatch A/B-measured optima (this problem, R3-R7):
//   DBUF=0: single-buffer m97 loop — best for K=1024 occupancy-rich QKV
//           (dbuf there: -1% R6; 2-deep: n/a).
//   DBUF=1: 1-deep dbuf, stage(next) before compute(cur), ONE __syncthreads
//           per K-step — best for grid-limited N=1024 shapes (FFN-out 98->81
//           us, 838 TF). 2-deep counted-vmcnt variants measured NEUTRAL
//           (R7: +4 us) or WORSE with sched_barrier pinning (R4: +10 us) —
//           in a 4-wave lockstep block, one barrier/K-step is optimal.
// EPI: 1: bf16(f32(aux1)+acc); 4: f32: bf16(aux1)+bf16(aux2)*acc -> float;
//      5: QKV fused split (N=3072): seg0->outp, seg1->aux1, seg2->aux2
// ---------------------------------------------------------------------------
template<int EPI, int DBUF>
__global__ __launch_bounds__(256)
void gemm_bt(const u16* __restrict__ A, const u16* __restrict__ B,
             int M, int N, int K,
             void* __restrict__ outp,
             const void* __restrict__ aux1, const void* __restrict__ aux2)
{
    __shared__ u16 lA[(1 + DBUF) * 128 * 64];
    __shared__ u16 lB[(1 + DBUF) * 128 * 64];
    const int tid  = threadIdx.x;
    const int wave = tid >> 6;
    const int lane = tid & 63;
    const int q    = lane >> 4;
    const int l16  = lane & 15;
    const long mBase = (long)blockIdx.x * 128;
    const long nBase = (long)blockIdx.y * 128;
    const int wm = (wave >> 1) * 64;
    const int wn = (wave & 1) * 64;

    f32x4 acc[4][4];
#pragma unroll
    for (int i = 0; i < 4; ++i)
#pragma unroll
        for (int j = 0; j < 4; ++j)
#pragma unroll
            for (int r = 0; r < 4; ++r) acc[i][j][r] = 0.f;

    const int srow = tid >> 3;
    const int scol = ((tid & 7) ^ (srow & 7)) * 8;
    const int ldsW = wave * 512;
    const int swz = l16 & 7;

    if (DBUF == 0) {
        for (int kb = 0; kb < K; kb += 64) {
            __syncthreads();
#pragma unroll
            for (int c = 0; c < 4; ++c) {
                const int row = c * 32 + srow;
                const u16* ga = A + (mBase + row) * (long)K + kb + scol;
                const u16* gb = B + (nBase + row) * (long)K + kb + scol;
                __builtin_amdgcn_global_load_lds(
                    (const __attribute__((address_space(1))) void*)ga,
                    (__attribute__((address_space(3))) void*)(lA + c * 2048 + ldsW),
                    16, 0, 0);
                __builtin_amdgcn_global_load_lds(
                    (const __attribute__((address_space(1))) void*)gb,
                    (__attribute__((address_space(3))) void*)(lB + c * 2048 + ldsW),
                    16, 0, 0);
            }
            __syncthreads();
#pragma unroll
            for (int ks = 0; ks < 2; ++ks) {
                const int grp = ((ks * 4 + q) ^ swz) * 8;
                bf16x8 af[4], bfm[4];
#pragma unroll
                for (int i = 0; i < 4; ++i) {
                    af[i]  = *(const bf16x8*)(lA + (wm + i * 16 + l16) * 64 + grp);
                    bfm[i] = *(const bf16x8*)(lB + (wn + i * 16 + l16) * 64 + grp);
                }
#pragma unroll
                for (int i = 0; i < 4; ++i)
#pragma unroll
                    for (int j = 0; j < 4; ++j)
                        acc[i][j] = __builtin_amdgcn_mfma_f32_16x16x32_bf16(
                            af[i], bfm[j], acc[i][j], 0, 0, 0);
            }
        }
    } else {
        // ---- 1-deep dbuf: stage(next) overlaps compute(cur) ----
#pragma unroll
        for (int c = 0; c < 4; ++c) {
            const int row = c * 32 + srow;
            const u16* ga = A + (mBase + row) * (long)K + scol;
            const u16* gb = B + (nBase + row) * (long)K + scol;
            __builtin_amdgcn_global_load_lds(
                (const __attribute__((address_space(1))) void*)ga,
                (__attribute__((address_space(3))) void*)(lA + c * 2048 + ldsW),
                16, 0, 0);
            __builtin_amdgcn_global_load_lds(
                (const __attribute__((address_space(1))) void*)gb,
                (__attribute__((address_space(3))) void*)(lB + c * 2048 + ldsW),
                16, 0, 0);
        }
        __syncthreads();            // drains vmcnt -> buf0 ready
        int cur = 0;
        for (int kb = 0; kb < K; kb += 64) {
            if (kb + 64 < K) {      // issue next tile's loads (async)
                const int nb = (cur ^ 1) * 8192;
#pragma unroll
                for (int c = 0; c < 4; ++c) {
                    const int row = c * 32 + srow;
                    const u16* ga = A + (mBase + row) * (long)K + kb + 64 + scol;
                    const u16* gb = B + (nBase + row) * (long)K + kb + 64 + scol;
                    __builtin_amdgcn_global_load_lds(
                        (const __attribute__((address_space(1))) void*)ga,
                        (__attribute__((address_space(3))) void*)(lA + nb + c * 2048 + ldsW),
                        16, 0, 0);
                    __builtin_amdgcn_global_load_lds(
                        (const __attribute__((address_space(1))) void*)gb,
                        (__attribute__((address_space(3))) void*)(lB + nb + c * 2048 + ldsW),
                        16, 0, 0);
                }
            }
            const u16* bA = lA + cur * 8192;
            const u16* bB = lB + cur * 8192;
#pragma unroll
            for (int ks = 0; ks < 2; ++ks) {
                const int grp = ((ks * 4 + q) ^ swz) * 8;
                bf16x8 af[4], bfm[4];
#pragma unroll
                for (int i = 0; i < 4; ++i) {
                    af[i]  = *(const bf16x8*)(bA + (wm + i * 16 + l16) * 64 + grp);
                    bfm[i] = *(const bf16x8*)(bB + (wn + i * 16 + l16) * 64 + grp);
                }
#pragma unroll
                for (int i = 0; i < 4; ++i)
#pragma unroll
                    for (int j = 0; j < 4; ++j)
                        acc[i][j] = __builtin_amdgcn_mfma_f32_16x16x32_bf16(
                            af[i], bfm[j], acc[i][j], 0, 0, 0);
            }
            // one barrier per step: all waves done reading buf[cur] AND
            // (via full drain) next-tile loads have landed in buf[cur^1]
            __syncthreads();
            cur ^= 1;
        }
    }

    if (EPI == 5) {
        const long seg = nBase >> 10;
        u16* optr = (u16*)(seg == 0 ? outp : seg == 1 ? (void*)aux1 : (void*)aux2);
        const long cb = (nBase & 1023) + wn + l16;
#pragma unroll
        for (int i = 0; i < 4; ++i)
#pragma unroll
            for (int r = 0; r < 4; ++r) {
                const long rowOff = (mBase + wm + i * 16 + q * 4 + r) * 1024 + cb;
#pragma unroll
                for (int j = 0; j < 4; ++j)
                    optr[rowOff + j * 16] = f2bf(acc[i][j][r]);
            }
    } else {
        const long colBase = nBase + wn + l16;
#pragma unroll
        for (int i = 0; i < 4; ++i) {
#pragma unroll
            for (int r = 0; r < 4; ++r) {
                const long row = mBase + wm + i * 16 + q * 4 + r;
                const long rowOff = row * (long)N;
#pragma unroll
                for (int j = 0; j < 4; ++j) {
                    const long idx = rowOff + colBase + j * 16;
                    const float val = acc[i][j][r];
                    if (EPI == 1) {
                        ((u16*)outp)[idx] = f2bf(((const float*)aux1)[idx] + val);
                    } else {
                        const float t = bf2f(((const u16*)aux1)[idx])
                                      + bf2f(((const u16*)aux2)[idx]) * val;
                        ((float*)outp)[idx] = t;
                    }
                }
            }
        }
    }
}

// ---------------------------------------------------------------------------
// fp8-MX GEMM (FFN-in): out = A[M,K]fp8 @ B[N,K]^T fp8, K=1024, N=5120.
// mfma_scale_f32_16x16x128_f8f6f4, BK=128 bytes, 128-B LDS rows, XOR swizzle
// on 16-B units. scale_a=127 (x1, activations), scale_b=123 (x2^-4,
// compensates weight x16 prescale). Epilogue: n<4096: relu^2 -> kk bf16
// (stride 4096); else sigmoid -> rp bf16 (stride 1024).
// ---------------------------------------------------------------------------
__global__ __launch_bounds__(256)
void gemm_f8(const u8* __restrict__ A, const u8* __restrict__ B,
             int M, int N, int K,
             u16* __restrict__ kk, u16* __restrict__ rp)
{
    __shared__ __align__(16) u8 lA[128 * 128];
    __shared__ __align__(16) u8 lB[128 * 128];
    const int tid  = threadIdx.x;
    const int wave = tid >> 6;
    const int lane = tid & 63;
    const int q    = lane >> 4;
    const int l16  = lane & 15;
    const long mBase = (long)blockIdx.x * 128;
    const long nBase = (long)blockIdx.y * 128;
    const int wm = (wave >> 1) * 64;
    const int wn = (wave & 1) * 64;

    f32x4 acc[4][4];
#pragma unroll
    for (int i = 0; i < 4; ++i)
#pragma unroll
        for (int j = 0; j < 4; ++j)
#pragma unroll
            for (int r = 0; r < 4; ++r) acc[i][j][r] = 0.f;

    const int srow  = tid >> 3;                       // 8 lanes per 128-B row
    const int scolB = ((tid & 7) ^ (srow & 7)) * 16;  // swizzled 16-B unit
    const int ldsW  = wave * 1024;
    const int swz   = l16 & 7;

    for (int kb = 0; kb < K; kb += 128) {
        __syncthreads();
#pragma unroll
        for (int c = 0; c < 4; ++c) {
            const int row = c * 32 + srow;
            const u8* ga = A + (mBase + row) * (long)K + kb + scolB;
            const u8* gb = B + (nBase + row) * (long)K + kb + scolB;
            __builtin_amdgcn_global_load_lds(
                (const __attribute__((address_space(1))) void*)ga,
                (__attribute__((address_space(3))) void*)(lA + c * 4096 + ldsW),
                16, 0, 0);
            __builtin_amdgcn_global_load_lds(
                (const __attribute__((address_space(1))) void*)gb,
                (__attribute__((address_space(3))) void*)(lB + c * 4096 + ldsW),
                16, 0, 0);
        }
        __syncthreads();
        // fragment: lane reads 32 B = 16-B units {2q, 2q+1} XOR swz.
        // XOR flips only unit bit0 within an aligned pair; the resulting
        // k-halves swap identically on A and B (same swz per lane) -> exact.
        const int u0 = ((2 * q) ^ swz) * 16;
        const int u1 = ((2 * q + 1) ^ swz) * 16;
        i32x8 af[4], bfm[4];
#pragma unroll
        for (int i = 0; i < 4; ++i) {
            {
                const u8* base = lA + (wm + i * 16 + l16) * 128;
                const uint4 lo = *(const uint4*)(base + u0);
                const uint4 hi = *(const uint4*)(base + u1);
                af[i][0] = lo.x; af[i][1] = lo.y; af[i][2] = lo.z; af[i][3] = lo.w;
                af[i][4] = hi.x; af[i][5] = hi.y; af[i][6] = hi.z; af[i][7] = hi.w;
            }
            {
                const u8* base = lB + (wn + i * 16 + l16) * 128;
                const uint4 lo = *(const uint4*)(base + u0);
                const uint4 hi = *(const uint4*)(base + u1);
                bfm[i][0] = lo.x; bfm[i][1] = lo.y; bfm[i][2] = lo.z; bfm[i][3] = lo.w;
                bfm[i][4] = hi.x; bfm[i][5] = hi.y; bfm[i][6] = hi.z; bfm[i][7] = hi.w;
            }
        }
#pragma unroll
        for (int i = 0; i < 4; ++i)
#pragma unroll
            for (int j = 0; j < 4; ++j)
                acc[i][j] = __builtin_amdgcn_mfma_scale_f32_16x16x128_f8f6f4(
                    af[i], bfm[j], acc[i][j], 0, 0, 0, 127, 0, 123);
    }

    // epilogue (C/D layout: col=lane&15, row=quad*4+reg — shape-determined)
    u16* optr; long sN, cb;
    if (nBase < 4096) { optr = kk; sN = 4096; cb = nBase + wn + l16; }
    else              { optr = rp; sN = 1024; cb = (nBase - 4096) + wn + l16; }
#pragma unroll
    for (int i = 0; i < 4; ++i)
#pragma unroll
        for (int r = 0; r < 4; ++r) {
            const long rowOff = (mBase + wm + i * 16 + q * 4 + r) * sN + cb;
#pragma unroll
            for (int j = 0; j < 4; ++j) {
                const float val = acc[i][j][r];
                float t;
                if (nBase < 4096) t = val > 0.f ? val * val : 0.f;
                else t = __fdividef(1.f, 1.f + __expf(-val));
                optr[rowOff + j * 16] = f2bf(t);
            }
        }
}

// ---------------------------------------------------------------------------
// Chunked WKV scan, phase 1: per-chunk (a,b,p) summary, both dirs.
// ---------------------------------------------------------------------------
__global__ __launch_bounds__(64)
void wkv_sum(const u16* __restrict__ kbuf, const u16* __restrict__ vbuf,
             const float* __restrict__ decay,
             float* __restrict__ sumA, float* __restrict__ sumB,
             float* __restrict__ sumP)
{
    const int c   = blockIdx.x * 64 + threadIdx.x;
    const int bt  = blockIdx.y;
    const int dir = blockIdx.z & 1;
    const int g   = blockIdx.z >> 1;
    const long base = (long)bt * (1024 * 1024) + c;
    const long stride = dir ? -1024 : 1024;
    long idx = dir ? base + (long)(1023 - g * TCH) * 1024
                   : base + (long)(g * TCH) * 1024;
    const float w = -__expf(decay[c]);
    float a = 0.f, b = 0.f, p = -1e38f;

    float kq[8], vq[8];
#pragma unroll
    for (int j = 0; j < 8; ++j) {
        kq[j] = bf2f(kbuf[idx + j * stride]);
        vq[j] = bf2f(vbuf[idx + j * stride]);
    }
    for (int tb = 0; tb < TCH / 8; ++tb) {
        float kn[8], vn[8];
        if (tb < TCH / 8 - 1) {
#pragma unroll
            for (int j = 0; j < 8; ++j) {
                kn[j] = bf2f(kbuf[idx + (j + 8) * stride]);
                vn[j] = bf2f(vbuf[idx + (j + 8) * stride]);
            }
        }
#pragma unroll
        for (int j = 0; j < 8; ++j) {
            const float kk = kq[j], vv = vq[j];
            const float pw = p + w;
            const float d  = pw - kk;
            const float e  = __expf(-fabsf(d));
            const float f1 = d >= 0.f ? 1.f : e;
            const float f2 = d >= 0.f ? e : 1.f;
            a = f1 * a + f2 * vv;
            b = f1 * b + f2;
            p = fmaxf(pw, kk);
        }
#pragma unroll
        for (int j = 0; j < 8; ++j) { kq[j] = kn[j]; vq[j] = vn[j]; }
        idx += 8 * stride;
    }
    const int sidx = (((dir * GCH + g) * 8 + bt) << 10) + c;
    sumA[sidx] = a; sumB[sidx] = b; sumP[sidx] = p;
}

// ---------------------------------------------------------------------------
// Phase 2 fused: fwd pass -> LDS, bwd pass + sigmoid(r)*0.5*(f+b) -> bf16.
// ---------------------------------------------------------------------------
__global__ __launch_bounds__(64)
void wkv_out2(const u16* __restrict__ kbuf, const u16* __restrict__ vbuf,
              const float* __restrict__ decay, const float* __restrict__ uarr,
              const float* __restrict__ sumA, const float* __restrict__ sumB,
              const float* __restrict__ sumP,
              const u16* __restrict__ rpre, u16* __restrict__ rwkv)
{
    __shared__ float fbuf[TCH * 64];
    const int lane = threadIdx.x;
    const int c   = blockIdx.x * 64 + lane;
    const int bt  = blockIdx.y;
    const int g   = blockIdx.z;
    const long base = (long)bt * (1024 * 1024) + c;
    const long rowBase = base + (long)(g * TCH) * 1024;
    const float w  = -__expf(decay[c]);
    const float uu = uarr[c];

    {
        float a = 0.f, b = 0.f, p = -1e38f;
        for (int gg = 0; gg < g; ++gg) {
            const int sidx = ((gg * 8 + bt) << 10) + c;
            const float a2 = sumA[sidx], b2 = sumB[sidx], p2 = sumP[sidx];
            const float pd = p + w * (float)TCH;
            const float d  = pd - p2;
            const float e  = __expf(-fabsf(d));
            const float x1 = d >= 0.f ? 1.f : e;
            const float x2 = d >= 0.f ? e : 1.f;
            a = x1 * a + x2 * a2;
            b = x1 * b + x2 * b2;
            p = fmaxf(pd, p2);
        }
        long idx = rowBase;
        float kq[8], vq[8];
#pragma unroll
        for (int j = 0; j < 8; ++j) {
            kq[j] = bf2f(kbuf[idx + j * 1024]);
            vq[j] = bf2f(vbuf[idx + j * 1024]);
        }
        for (int tb = 0; tb < TCH / 8; ++tb) {
            float kn[8], vn[8];
            if (tb < TCH / 8 - 1) {
#pragma unroll
                for (int j = 0; j < 8; ++j) {
                    kn[j] = bf2f(kbuf[idx + (j + 8) * 1024]);
                    vn[j] = bf2f(vbuf[idx + (j + 8) * 1024]);
                }
            }
#pragma unroll
            for (int j = 0; j < 8; ++j) {
                const float kk = kq[j], vv = vq[j];
                const float uk = uu + kk;
                const float d1 = p - uk;
                const float e  = __expf(-fabsf(d1));
                const float e1 = d1 >= 0.f ? 1.f : e;
                const float e2 = d1 >= 0.f ? e : 1.f;
                fbuf[(tb * 8 + j) * 64 + lane] =
                    __fdividef(e1 * a + e2 * vv, e1 * b + e2);
                const float pw = p + w;
                const float d2 = pw - kk;
                const float e_ = __expf(-fabsf(d2));
                const float f1 = d2 >= 0.f ? 1.f : e_;
                const float f2 = d2 >= 0.f ? e_ : 1.f;
                a = f1 * a + f2 * vv;
                b = f1 * b + f2;
                p = fmaxf(pw, kk);
            }
#pragma unroll
            for (int j = 0; j < 8; ++j) { kq[j] = kn[j]; vq[j] = vn[j]; }
            idx += 8 * 1024;
        }
    }
    __syncthreads();

    {
        float a = 0.f, b = 0.f, p = -1e38f;
        const int gb = GCH - 1 - g;
        for (int gg = 0; gg < gb; ++gg) {
            const int sidx = (((GCH + gg) * 8 + bt) << 10) + c;
            const float a2 = sumA[sidx], b2 = sumB[sidx], p2 = sumP[sidx];
            const float pd = p + w * (float)TCH;
            const float d  = pd - p2;
            const float e  = __expf(-fabsf(d));
            const float x1 = d >= 0.f ? 1.f : e;
            const float x2 = d >= 0.f ? e : 1.f;
            a = x1 * a + x2 * a2;
            b = x1 * b + x2 * b2;
            p = fmaxf(pd, p2);
        }
        long idx = rowBase + (long)(TCH - 1) * 1024;
        float kq[8], vq[8];
#pragma unroll
        for (int j = 0; j < 8; ++j) {
            kq[j] = bf2f(kbuf[idx - j * 1024]);
            vq[j] = bf2f(vbuf[idx - j * 1024]);
        }
        for (int tb = 0; tb < TCH / 8; ++tb) {
            float kn[8], vn[8];
            if (tb < TCH / 8 - 1) {
#pragma unroll
                for (int j = 0; j < 8; ++j) {
                    kn[j] = bf2f(kbuf[idx - (j + 8) * 1024]);
                    vn[j] = bf2f(vbuf[idx - (j + 8) * 1024]);
                }
            }
#pragma unroll
            for (int j = 0; j < 8; ++j) {
                const long ii = idx - (long)j * 1024;
                const int  tl = TCH - 1 - (tb * 8 + j);
                const float kk = kq[j], vv = vq[j];
                const float uk = uu + kk;
                const float d1 = p - uk;
                const float e  = __expf(-fabsf(d1));
                const float e1 = d1 >= 0.f ? 1.f : e;
                const float e2 = d1 >= 0.f ? e : 1.f;
                const float ob = __fdividef(e1 * a + e2 * vv, e1 * b + e2);
                const float of = fbuf[tl * 64 + lane];
                const float rr = __fdividef(1.f, 1.f + __expf(-bf2f(rpre[ii])));
                rwkv[ii] = f2bf(rr * 0.5f * (of + ob));
                const float pw = p + w;
                const float d2 = pw - kk;
                const float e_ = __expf(-fabsf(d2));
                const float f1 = d2 >= 0.f ? 1.f : e_;
                const float f2 = d2 >= 0.f ? e_ : 1.f;
                a = f1 * a + f2 * vv;
                b = f1 * b + f2;
                p = fmaxf(pw, kk);
            }
#pragma unroll
            for (int j = 0; j < 8; ++j) { kq[j] = kn[j]; vq[j] = vn[j]; }
            idx -= 8 * 1024;
        }
    }
}

// ---------------------------------------------------------------------------
extern "C" void kernel_launch(void* const* d_in, const int* in_sizes, int n_in,
                              void* d_out, int out_size, void* d_ws, size_t ws_size,
                              hipStream_t stream)
{
    (void)in_sizes; (void)n_in; (void)out_size; (void)ws_size;
    const float* x     = (const float*)d_in[0];
    const float* ln1w  = (const float*)d_in[1];
    const float* ln1b  = (const float*)d_in[2];
    const float* ln2w  = (const float*)d_in[3];
    const float* ln2b  = (const float*)d_in[4];
    const float* Wr    = (const float*)d_in[5];
    const float* Wk    = (const float*)d_in[6];
    const float* Wv    = (const float*)d_in[7];
    const float* Wo    = (const float*)d_in[8];
    const float* decay = (const float*)d_in[9];
    const float* uarr  = (const float*)d_in[10];
    const float* Wfk   = (const float*)d_in[11];
    const float* Wfv   = (const float*)d_in[12];
    const float* Wfr   = (const float*)d_in[13];

    const int M = 8192, C = 1024, C4 = 4096;
    const size_t MB = 1024u * 1024u;
    char* ws = (char*)d_ws;
    u16*  X2    = (u16*)(ws);                // [0,16)    x after time-mix (bf16)
    u16*  XN    = (u16*)(ws + 16 * MB);      // [16,32)   xn1 bf16
    u8*   XN8   = (u8*)(ws + 16 * MB);       // [16,24)   xn2 fp8 (reuse, xn1 dead)
    u16*  RP    = (u16*)(ws + 32 * MB);      // [32,48)   r_pre, later ffn sigmoid
    u16*  KB    = (u16*)(ws + 48 * MB);      // [48,64)   k
    u16*  VB    = (u16*)(ws + 64 * MB);      // [64,80)   v
    u16*  RWKV  = (u16*)(ws + 80 * MB);      // [80,96)   combined rwkv
    u16*  KK    = (u16*)(ws + 48 * MB);      // [48,112)  ffn relu^2 key (reuse)
    float* sumA = (float*)(ws + 112 * MB);
    float* sumB = (float*)(ws + 113 * MB);
    float* sumP = (float*)(ws + 114 * MB);
    u16*  WrB   = (u16*)(ws + 116 * MB);     // bf16 [Wr;Wk;Wv] contiguous
    u16*  WkB   = (u16*)(ws + 118 * MB);
    u16*  WvB   = (u16*)(ws + 120 * MB);
    u16*  WoB   = (u16*)(ws + 122 * MB);
    u8*   Wf8   = (u8*)(ws + 124 * MB);      // fp8 [Wfk;Wfr] x16, 5 MB
    u8*   Wfr8  = (u8*)(ws + 128 * MB);
    u16*  WfvB  = (u16*)(ws + 130 * MB);     // bf16 8 MB -> ends 138 MB

    const dim3 blk(256);
    const int n4_1M = C * C / 4, n4_4M = C * C4 / 4;

    WSegs segs;
    segs.src[0] = Wr;  segs.dst[0] = WrB;  segs.n4[0] = n4_1M; segs.mode[0] = 0;
    segs.src[1] = Wk;  segs.dst[1] = WkB;  segs.n4[1] = n4_1M; segs.mode[1] = 0;
    segs.src[2] = Wv;  segs.dst[2] = WvB;  segs.n4[2] = n4_1M; segs.mode[2] = 0;
    segs.src[3] = Wo;  segs.dst[3] = WoB;  segs.n4[3] = n4_1M; segs.mode[3] = 0;
    segs.src[4] = Wfk; segs.dst[4] = Wf8;  segs.n4[4] = n4_4M; segs.mode[4] = 1;
    segs.src[5] = Wfr; segs.dst[5] = Wfr8; segs.n4[5] = n4_1M; segs.mode[5] = 1;
    segs.src[6] = Wfv; segs.dst[6] = WfvB; segs.n4[6] = n4_4M; segs.mode[6] = 0;
    wconv_all<<<dim3(n4_4M / 256, 7), blk, 0, stream>>>(segs);

    ln_kernel<0, 0><<<dim3(M), blk, 0, stream>>>(x, ln1w, ln1b, XN);
    gemm_bt<5, 0><<<dim3(M / 128, 3 * C / 128), blk, 0, stream>>>(
        XN, WrB, M, 3 * C, C, RP, KB, VB);
    wkv_sum<<<dim3(16, 8, 2 * GCH), dim3(64), 0, stream>>>(KB, VB, decay,
                                                           sumA, sumB, sumP);
    wkv_out2<<<dim3(16, 8, GCH), dim3(64), 0, stream>>>(KB, VB, decay, uarr,
                                                        sumA, sumB, sumP,
                                                        RP, RWKV);
    gemm_bt<1, 1><<<dim3(M / 128, C / 128), blk, 0, stream>>>(
        RWKV, WoB, M, C, C, X2, x, nullptr);
    ln_kernel<1, 1><<<dim3(M), blk, 0, stream>>>(X2, ln2w, ln2b, XN8);
    // fp8-MX fused FFN-in: N = 5120, B = [Wfk;Wfr] fp8 (x16 prescale)
    gemm_f8<<<dim3(M / 128, 5 * C / 128), blk, 0, stream>>>(
        XN8, Wf8, M, 5 * C, C, KK, RP);
    gemm_bt<4, 1><<<dim3(M / 128, C / 128), blk, 0, stream>>>(
        KK, WfvB, M, C, C4, d_out, X2, RP);
}